// Round 4
// baseline (642.280 us; speedup 1.0000x reference)
//
#include <hip/hip_runtime.h>
#include <math.h>

#define BATCH 2
#define SLEN 2048
#define DM 1024
#define NH 16
#define DK 64
#define STILES (SLEN / 64)  // 32

typedef __attribute__((ext_vector_type(8))) __bf16 bf16x8;
typedef __attribute__((ext_vector_type(4))) float f32x4;

__device__ __forceinline__ unsigned short f2bf(float x) {  // round-nearest
  unsigned u = __builtin_bit_cast(unsigned, x);
  unsigned r = (u + 0x7fffu + ((u >> 16) & 1u)) >> 16;
  return (unsigned short)r;
}
__device__ __forceinline__ float bf2f(unsigned short b) {
  unsigned u = ((unsigned)b) << 16;
  return __builtin_bit_cast(float, u);
}
// cheap truncation split: x ~= hi + lo to ~2^-16 relative
__device__ __forceinline__ void splitbf(float x, unsigned short& h,
                                        unsigned short& l) {
  unsigned u = __builtin_bit_cast(unsigned, x);
  h = (unsigned short)(u >> 16);
  float hf = __builtin_bit_cast(float, u & 0xffff0000u);
  l = (unsigned short)(__builtin_bit_cast(unsigned, x - hf) >> 16);
}

// ---------------------------------------------------------------------------
// Weight transpose+split: W[h][k][j] fp32 -> Wt[n=h*64+j][packed k] bf16,
// packed layout: per 32-k block: [hi32 | lo32] (row stride 2048).
// grid (16 kb64, 16 h, 3 which), block 256.
// ---------------------------------------------------------------------------
__global__ __launch_bounds__(256)
void convert_w(const float* __restrict__ Wq, const float* __restrict__ Wk,
               const float* __restrict__ Wv, unsigned short* __restrict__ Wqt,
               unsigned short* __restrict__ Wkt,
               unsigned short* __restrict__ Wvt) {
  const int kb = blockIdx.x, h = blockIdx.y, z = blockIdx.z;
  const float* W = (z == 0 ? Wq : z == 1 ? Wk : Wv) +
                   ((size_t)h * DM + kb * 64) * DK;
  unsigned short* D = (z == 0 ? Wqt : z == 1 ? Wkt : Wvt);

  __shared__ float T[64][65];
  const int tid = threadIdx.x;
  {
    int r = tid >> 2, c0 = (tid & 3) * 16;
#pragma unroll
    for (int i = 0; i < 4; ++i) {
      float4 f = *(const float4*)(W + (size_t)r * DK + c0 + i * 4);
      T[r][c0 + i * 4 + 0] = f.x;
      T[r][c0 + i * 4 + 1] = f.y;
      T[r][c0 + i * 4 + 2] = f.z;
      T[r][c0 + i * 4 + 3] = f.w;
    }
  }
  __syncthreads();
  int j = tid >> 2, p = tid & 3;
  int n = h * 64 + j;
  int kloc = p * 16;
  unsigned short hi[16], lo[16];
#pragma unroll
  for (int i = 0; i < 16; ++i) splitbf(T[kloc + i][j], hi[i], lo[i]);
  int kglob = kb * 64 + kloc;
  int col = (kglob >> 5) * 64 + (kglob & 31);
  uint4 uh, ul;
  uh.x = (unsigned)hi[0] | ((unsigned)hi[1] << 16);
  uh.y = (unsigned)hi[2] | ((unsigned)hi[3] << 16);
  uh.z = (unsigned)hi[4] | ((unsigned)hi[5] << 16);
  uh.w = (unsigned)hi[6] | ((unsigned)hi[7] << 16);
  *(uint4*)(D + (size_t)n * 2048 + col) = uh;
  uh.x = (unsigned)hi[8] | ((unsigned)hi[9] << 16);
  uh.y = (unsigned)hi[10] | ((unsigned)hi[11] << 16);
  uh.z = (unsigned)hi[12] | ((unsigned)hi[13] << 16);
  uh.w = (unsigned)hi[14] | ((unsigned)hi[15] << 16);
  *(uint4*)(D + (size_t)n * 2048 + col + 8) = uh;
  ul.x = (unsigned)lo[0] | ((unsigned)lo[1] << 16);
  ul.y = (unsigned)lo[2] | ((unsigned)lo[3] << 16);
  ul.z = (unsigned)lo[4] | ((unsigned)lo[5] << 16);
  ul.w = (unsigned)lo[6] | ((unsigned)lo[7] << 16);
  *(uint4*)(D + (size_t)n * 2048 + col + 32) = ul;
  ul.x = (unsigned)lo[8] | ((unsigned)lo[9] << 16);
  ul.y = (unsigned)lo[10] | ((unsigned)lo[11] << 16);
  ul.z = (unsigned)lo[12] | ((unsigned)lo[13] << 16);
  ul.w = (unsigned)lo[14] | ((unsigned)lo[15] << 16);
  *(uint4*)(D + (size_t)n * 2048 + col + 40) = ul;
}

// ---------------------------------------------------------------------------
// Split-MFMA projection GEMM: C[m,n] = sum_k A[m,k] Wt[n,k] + bias[n].
// 128m x 64n tile, BK=32, 256 thr / 4 waves; wave = 64m x 32n (4x2 MFMA
// tiles, 32 acc VGPRs). grid (16 ntile, 32 mt, 3 z) = 1536 blocks (6/CU);
// LDS 26 KB -> 6 blocks/CU. Occupancy was the round-3 limiter (19%).
// ---------------------------------------------------------------------------
#define LDA 68  // LDS row stride (bf16): 32 hi | 32 lo | pad 4

__global__ __launch_bounds__(256)
void proj_gemm(const float* __restrict__ Qin, const float* __restrict__ Kin,
               const float* __restrict__ Vin,
               const unsigned short* __restrict__ Wqt,
               const unsigned short* __restrict__ Wkt,
               const unsigned short* __restrict__ Wvt,
               const float* __restrict__ bq, const float* __restrict__ bk,
               const float* __restrict__ bv, unsigned short* __restrict__ q_all,
               unsigned short* __restrict__ k_all,
               unsigned short* __restrict__ vt) {
  const int ntile = blockIdx.x, mt = blockIdx.y, z = blockIdx.z;
  const float* A = (z == 0 ? Qin : z == 1 ? Kin : Vin);
  const unsigned short* B = (z == 0 ? Wqt : z == 1 ? Wkt : Wvt);
  const float* bias = (z == 0 ? bq : z == 1 ? bk : bv);

  __shared__ unsigned short As[128 * LDA];
  __shared__ unsigned short Bs[64 * LDA];

  const int tid = threadIdx.x;
  const int lane = tid & 63, w = tid >> 6;
  const int l15 = lane & 15, quad = lane >> 4;
  const int wm = (w & 1) * 64, wn = (w >> 1) * 32;

  const float* Ap = A + (size_t)(mt * 128) * DM;

  f32x4 acc[4][2];
#pragma unroll
  for (int i = 0; i < 4; ++i)
#pragma unroll
    for (int j = 0; j < 2; ++j) acc[i][j] = (f32x4){0.f, 0.f, 0.f, 0.f};

  for (int k0 = 0; k0 < DM; k0 += 32) {
    // stage A (128x32 fp32, inline split)
#pragma unroll
    for (int it = 0; it < 4; ++it) {
      int c = tid + it * 256;
      int r = c >> 3, seg = c & 7;
      float4 f = *(const float4*)(Ap + (size_t)r * DM + k0 + seg * 4);
      ushort4 h4, l4;
      splitbf(f.x, h4.x, l4.x);
      splitbf(f.y, h4.y, l4.y);
      splitbf(f.z, h4.z, l4.z);
      splitbf(f.w, h4.w, l4.w);
      *(ushort4*)&As[r * LDA + seg * 4] = h4;
      *(ushort4*)&As[r * LDA + 32 + seg * 4] = l4;
    }
    // stage B (64 rows x 64 packed ushorts, raw copy)
#pragma unroll
    for (int it = 0; it < 2; ++it) {
      int c = tid + it * 256;
      int r = c >> 3, seg = c & 7;
      *(uint4*)&Bs[r * LDA + seg * 8] =
          *(const uint4*)(B + (size_t)(ntile * 64 + r) * 2048 +
                          (k0 >> 5) * 64 + seg * 8);
    }
    __syncthreads();

    bf16x8 ah[4], al[4];
#pragma unroll
    for (int i = 0; i < 4; ++i) {
      const unsigned short* p = &As[(wm + i * 16 + l15) * LDA + quad * 8];
      ah[i] = *(const bf16x8*)(p);
      al[i] = *(const bf16x8*)(p + 32);
    }
#pragma unroll
    for (int j = 0; j < 2; ++j) {
      const unsigned short* p = &Bs[(wn + j * 16 + l15) * LDA + quad * 8];
      bf16x8 bh = *(const bf16x8*)(p);
      bf16x8 bl = *(const bf16x8*)(p + 32);
#pragma unroll
      for (int i = 0; i < 4; ++i) {
        acc[i][j] = __builtin_amdgcn_mfma_f32_16x16x32_bf16(ah[i], bh, acc[i][j], 0, 0, 0);
        acc[i][j] = __builtin_amdgcn_mfma_f32_16x16x32_bf16(al[i], bh, acc[i][j], 0, 0, 0);
        acc[i][j] = __builtin_amdgcn_mfma_f32_16x16x32_bf16(ah[i], bl, acc[i][j], 0, 0, 0);
      }
    }
    __syncthreads();
  }

  if (z <= 1) {
    unsigned short* dst = (z == 0 ? q_all : k_all);
#pragma unroll
    for (int i = 0; i < 4; ++i)
#pragma unroll
      for (int j = 0; j < 2; ++j) {
        int n = ntile * 64 + wn + j * 16 + l15;
        int col = (n >> 5) * 64 + (n & 31);
        float bn = bias[n];
#pragma unroll
        for (int r = 0; r < 4; ++r) {
          int m = mt * 128 + wm + i * 16 + quad * 4 + r;
          unsigned short hh, ll;
          splitbf(acc[i][j][r] + bn, hh, ll);
          dst[(size_t)m * 2048 + col] = hh;
          dst[(size_t)m * 2048 + col + 32] = ll;
        }
      }
  } else {
#pragma unroll
    for (int i = 0; i < 4; ++i)
#pragma unroll
      for (int j = 0; j < 2; ++j) {
        int n = ntile * 64 + wn + j * 16 + l15;
        int h = n >> 6, d = n & 63;
        float bn = bias[n];
        int m0 = mt * 128 + wm + i * 16 + quad * 4;
        int b = m0 >> 11, s = m0 & 2047;
        ushort4 h4, l4;
        splitbf(acc[i][j][0] + bn, h4.x, l4.x);
        splitbf(acc[i][j][1] + bn, h4.y, l4.y);
        splitbf(acc[i][j][2] + bn, h4.z, l4.z);
        splitbf(acc[i][j][3] + bn, h4.w, l4.w);
        size_t base = ((size_t)(b * NH + h) * 128 + d) * 2048 + s;
        *(ushort4*)(vt + base) = h4;
        *(ushort4*)(vt + base + (size_t)64 * 2048) = l4;
      }
  }
}

// ---------------------------------------------------------------------------
// Output GEMM: out[m,n] = sum_k a_all[m,k] Wo[n,k] + bo[n], fp32 out.
// Same 128x64 tiling as proj_gemm. grid (16 ntile, 32 mt) = 512 blocks.
// ---------------------------------------------------------------------------
__global__ __launch_bounds__(256)
void out_gemm(const unsigned short* __restrict__ a_all,
              const float* __restrict__ Wo, const float* __restrict__ bo,
              float* __restrict__ out) {
  const int ntile = blockIdx.x, mt = blockIdx.y;

  __shared__ unsigned short As[128 * LDA];
  __shared__ unsigned short Bs[64 * LDA];

  const int tid = threadIdx.x;
  const int lane = tid & 63, w = tid >> 6;
  const int l15 = lane & 15, quad = lane >> 4;
  const int wm = (w & 1) * 64, wn = (w >> 1) * 32;

  f32x4 acc[4][2];
#pragma unroll
  for (int i = 0; i < 4; ++i)
#pragma unroll
    for (int j = 0; j < 2; ++j) acc[i][j] = (f32x4){0.f, 0.f, 0.f, 0.f};

  for (int k0 = 0; k0 < DM; k0 += 32) {
    // stage A (packed bf16, raw copy)
#pragma unroll
    for (int it = 0; it < 4; ++it) {
      int c = tid + it * 256;
      int r = c >> 3, seg = c & 7;
      *(uint4*)&As[r * LDA + seg * 8] =
          *(const uint4*)(a_all + (size_t)(mt * 128 + r) * 2048 +
                          (k0 >> 5) * 64 + seg * 8);
    }
    // stage B (Wo fp32 64x32, inline split)
#pragma unroll
    for (int it = 0; it < 2; ++it) {
      int c = tid + it * 256;
      int r = c >> 3, seg = c & 7;
      float4 f = *(const float4*)(Wo + (size_t)(ntile * 64 + r) * DM + k0 +
                                  seg * 4);
      ushort4 h4, l4;
      splitbf(f.x, h4.x, l4.x);
      splitbf(f.y, h4.y, l4.y);
      splitbf(f.z, h4.z, l4.z);
      splitbf(f.w, h4.w, l4.w);
      *(ushort4*)&Bs[r * LDA + seg * 4] = h4;
      *(ushort4*)&Bs[r * LDA + 32 + seg * 4] = l4;
    }
    __syncthreads();

    bf16x8 ah[4], al[4];
#pragma unroll
    for (int i = 0; i < 4; ++i) {
      const unsigned short* p = &As[(wm + i * 16 + l15) * LDA + quad * 8];
      ah[i] = *(const bf16x8*)(p);
      al[i] = *(const bf16x8*)(p + 32);
    }
#pragma unroll
    for (int j = 0; j < 2; ++j) {
      const unsigned short* p = &Bs[(wn + j * 16 + l15) * LDA + quad * 8];
      bf16x8 bh = *(const bf16x8*)(p);
      bf16x8 bl = *(const bf16x8*)(p + 32);
#pragma unroll
      for (int i = 0; i < 4; ++i) {
        acc[i][j] = __builtin_amdgcn_mfma_f32_16x16x32_bf16(ah[i], bh, acc[i][j], 0, 0, 0);
        acc[i][j] = __builtin_amdgcn_mfma_f32_16x16x32_bf16(al[i], bh, acc[i][j], 0, 0, 0);
        acc[i][j] = __builtin_amdgcn_mfma_f32_16x16x32_bf16(ah[i], bl, acc[i][j], 0, 0, 0);
      }
    }
    __syncthreads();
  }

#pragma unroll
  for (int i = 0; i < 4; ++i)
#pragma unroll
    for (int j = 0; j < 2; ++j) {
      int n = ntile * 64 + wn + j * 16 + l15;
      float bn = bo[n];
#pragma unroll
      for (int r = 0; r < 4; ++r) {
        int m = mt * 128 + wm + i * 16 + quad * 4 + r;
        out[(size_t)m * DM + n] = acc[i][j][r] + bn;
      }
    }
}

// ---------------------------------------------------------------------------
// MFMA flash attention (unchanged from round 3).
// ---------------------------------------------------------------------------
#define LDK 136
#define LDP 72

__global__ __launch_bounds__(256)
void attn_kernel(const unsigned short* __restrict__ q_all,
                 const unsigned short* __restrict__ k_all,
                 const unsigned short* __restrict__ vt,
                 unsigned short* __restrict__ a_all) {
  const int qt = blockIdx.x, h = blockIdx.y, b = blockIdx.z;
  const unsigned short* vp = vt + (size_t)(b * NH + h) * 128 * 2048;

  __shared__ unsigned short Ks[64 * LDK];
  __shared__ unsigned short Vs[64 * LDK];
  __shared__ unsigned short Ps[64 * LDP];

  const int tid = threadIdx.x;
  const int lane = tid & 63;
  const int w = tid >> 6;
  const int l15 = lane & 15;
  const int quad = lane >> 4;

  bf16x8 qf[2][2];
  {
    const unsigned short* qrow =
        q_all + (size_t)(b * SLEN + qt * 64 + w * 16 + l15) * 2048;
#pragma unroll
    for (int kb = 0; kb < 2; ++kb) {
      qf[kb][0] = *(const bf16x8*)(qrow + (2 * h + kb) * 64 + quad * 8);
      qf[kb][1] = *(const bf16x8*)(qrow + (2 * h + kb) * 64 + 32 + quad * 8);
    }
  }

  f32x4 o[4];
#pragma unroll
  for (int nt = 0; nt < 4; ++nt) o[nt] = (f32x4){0.f, 0.f, 0.f, 0.f};
  float lpart[4] = {0.f, 0.f, 0.f, 0.f};

  for (int kt = 0; kt < STILES; ++kt) {
    const unsigned short* ksrc =
        k_all + (size_t)(b * SLEN + kt * 64) * 2048 + 2 * h * 64;
#pragma unroll
    for (int it = 0; it < 4; ++it) {
      int ch = it * 256 + tid;
      int r = ch >> 4, seg = ch & 15;
      int g = seg >> 2;
      int lc = (g & 1) * 64 + (g >> 1) * 32 + (seg & 3) * 8;
      *(uint4*)(&Ks[r * LDK + lc]) =
          *(const uint4*)(ksrc + (size_t)r * 2048 + seg * 8);
    }
    const unsigned short* vsrc = vp + (size_t)(kt * 64);
#pragma unroll
    for (int it = 0; it < 4; ++it) {
      int ch = it * 256 + tid;
      int r = ch >> 3, c8 = (ch & 7) * 8;
      int lr = r & 63, lc = (r >> 6) * 64 + c8;
      *(uint4*)(&Vs[lr * LDK + lc]) =
          *(const uint4*)(vsrc + (size_t)r * 2048 + c8);
    }
    __syncthreads();

    f32x4 s[4];
#pragma unroll
    for (int ct = 0; ct < 4; ++ct) s[ct] = (f32x4){0.f, 0.f, 0.f, 0.f};
#pragma unroll
    for (int ct = 0; ct < 4; ++ct) {
#pragma unroll
      for (int kb = 0; kb < 2; ++kb) {
        const unsigned short* krow =
            &Ks[(ct * 16 + l15) * LDK + kb * 32 + quad * 8];
        bf16x8 kh = *(const bf16x8*)(krow);
        bf16x8 kl = *(const bf16x8*)(krow + 64);
        s[ct] = __builtin_amdgcn_mfma_f32_16x16x32_bf16(qf[kb][0], kh, s[ct], 0, 0, 0);
        s[ct] = __builtin_amdgcn_mfma_f32_16x16x32_bf16(qf[kb][0], kl, s[ct], 0, 0, 0);
        s[ct] = __builtin_amdgcn_mfma_f32_16x16x32_bf16(qf[kb][1], kh, s[ct], 0, 0, 0);
      }
    }

#pragma unroll
    for (int ct = 0; ct < 4; ++ct) {
#pragma unroll
      for (int r = 0; r < 4; ++r) {
        float e = __expf(s[ct][r] * 0.125f);
        lpart[r] += e;
        Ps[(w * 16 + quad * 4 + r) * LDP + ct * 16 + l15] = f2bf(e);
      }
    }
    __syncthreads();

#pragma unroll
    for (int kb = 0; kb < 2; ++kb) {
      bf16x8 pf = *(const bf16x8*)(&Ps[(w * 16 + l15) * LDP + kb * 32 + quad * 8]);
#pragma unroll
      for (int nt = 0; nt < 4; ++nt) {
        const unsigned short* vrow =
            &Vs[(nt * 16 + l15) * LDK + kb * 32 + quad * 8];
        bf16x8 vh = *(const bf16x8*)(vrow);
        bf16x8 vl = *(const bf16x8*)(vrow + 64);
        o[nt] = __builtin_amdgcn_mfma_f32_16x16x32_bf16(pf, vh, o[nt], 0, 0, 0);
        o[nt] = __builtin_amdgcn_mfma_f32_16x16x32_bf16(pf, vl, o[nt], 0, 0, 0);
      }
    }
    __syncthreads();
  }

  float inv[4];
#pragma unroll
  for (int r = 0; r < 4; ++r) {
    float lv = lpart[r];
#pragma unroll
    for (int m = 1; m < 16; m <<= 1) lv += __shfl_xor(lv, m, 64);
    inv[r] = 1.f / lv;
  }
#pragma unroll
  for (int nt = 0; nt < 4; ++nt) {
    int c = h * 64 + nt * 16 + l15;
    int pc = (c >> 5) * 64 + (c & 31);
#pragma unroll
    for (int r = 0; r < 4; ++r) {
      float val = o[nt][r] * inv[r];
      int row = qt * 64 + w * 16 + quad * 4 + r;
      size_t g = (size_t)(b * SLEN + row) * 2048 + pc;
      unsigned short hh, ll;
      splitbf(val, hh, ll);
      a_all[g] = hh;
      a_all[g + 32] = ll;
    }
  }
}

extern "C" void kernel_launch(void* const* d_in, const int* in_sizes, int n_in,
                              void* d_out, int out_size, void* d_ws,
                              size_t ws_size, hipStream_t stream) {
  (void)in_sizes; (void)n_in; (void)out_size; (void)ws_size;
  const float* Q = (const float*)d_in[0];
  const float* K = (const float*)d_in[1];
  const float* V = (const float*)d_in[2];
  const float* Wq = (const float*)d_in[3];
  const float* bq = (const float*)d_in[4];
  const float* Wk = (const float*)d_in[5];
  const float* bk = (const float*)d_in[6];
  const float* Wv = (const float*)d_in[7];
  const float* bv = (const float*)d_in[8];
  const float* Wo = (const float*)d_in[9];
  const float* bo = (const float*)d_in[10];
  float* out = (float*)d_out;

  unsigned short* us = (unsigned short*)d_ws;
  const size_t M8 = 8u * 1024 * 1024;
  unsigned short* q_all = us;
  unsigned short* k_all = us + M8;
  unsigned short* vt = us + 2 * M8;
  unsigned short* a_all = us + 3 * M8;
  unsigned short* Wqt = a_all;
  unsigned short* Wkt = a_all + 2 * 1024 * 1024;
  unsigned short* Wvt = a_all + 4 * 1024 * 1024;

  convert_w<<<dim3(16, 16, 3), 256, 0, stream>>>(Wq, Wk, Wv, Wqt, Wkt, Wvt);
  proj_gemm<<<dim3(16, 32, 3), 256, 0, stream>>>(Q, K, V, Wqt, Wkt, Wvt, bq,
                                                 bk, bv, q_all, k_all, vt);
  attn_kernel<<<dim3(STILES, NH, BATCH), 256, 0, stream>>>(q_all, k_all, vt,
                                                           a_all);
  out_gemm<<<dim3(16, 32), 256, 0, stream>>>(a_all, Wo, bo, out);
}

// Round 5
// 568.988 us; speedup vs baseline: 1.1288x; 1.1288x over previous
//
#include <hip/hip_runtime.h>
#include <math.h>

#define BATCH 2
#define SLEN 2048
#define DM 1024
#define NH 16
#define DK 64
#define STILES (SLEN / 64)  // 32

typedef __attribute__((ext_vector_type(8))) __bf16 bf16x8;
typedef __attribute__((ext_vector_type(4))) float f32x4;

__device__ __forceinline__ unsigned short f2bf(float x) {  // round-nearest
  unsigned u = __builtin_bit_cast(unsigned, x);
  unsigned r = (u + 0x7fffu + ((u >> 16) & 1u)) >> 16;
  return (unsigned short)r;
}
__device__ __forceinline__ float bf2f(unsigned short b) {
  unsigned u = ((unsigned)b) << 16;
  return __builtin_bit_cast(float, u);
}
// cheap truncation split: x ~= hi + lo to ~2^-16 relative
__device__ __forceinline__ void splitbf(float x, unsigned short& h,
                                        unsigned short& l) {
  unsigned u = __builtin_bit_cast(unsigned, x);
  h = (unsigned short)(u >> 16);
  float hf = __builtin_bit_cast(float, u & 0xffff0000u);
  l = (unsigned short)(__builtin_bit_cast(unsigned, x - hf) >> 16);
}

// async global->LDS, 16 B per lane; LDS dest = wave-uniform base + lane*16
__device__ __forceinline__ void gld16(const unsigned short* g,
                                      unsigned short* l) {
  __builtin_amdgcn_global_load_lds(
      (const __attribute__((address_space(1))) void*)g,
      (__attribute__((address_space(3))) void*)l, 16, 0, 0);
}

// ---------------------------------------------------------------------------
// Weight transpose+split: W[h][k][j] fp32 -> Wt[n=h*64+j][packed k] bf16,
// packed layout: per 32-k block: [hi32 | lo32] (row stride 2048).
// ---------------------------------------------------------------------------
__global__ __launch_bounds__(256)
void convert_w(const float* __restrict__ Wq, const float* __restrict__ Wk,
               const float* __restrict__ Wv, unsigned short* __restrict__ Wqt,
               unsigned short* __restrict__ Wkt,
               unsigned short* __restrict__ Wvt) {
  const int kb = blockIdx.x, h = blockIdx.y, z = blockIdx.z;
  const float* W = (z == 0 ? Wq : z == 1 ? Wk : Wv) +
                   ((size_t)h * DM + kb * 64) * DK;
  unsigned short* D = (z == 0 ? Wqt : z == 1 ? Wkt : Wvt);

  __shared__ float T[64][65];
  const int tid = threadIdx.x;
  {
    int r = tid >> 2, c0 = (tid & 3) * 16;
#pragma unroll
    for (int i = 0; i < 4; ++i) {
      float4 f = *(const float4*)(W + (size_t)r * DK + c0 + i * 4);
      T[r][c0 + i * 4 + 0] = f.x;
      T[r][c0 + i * 4 + 1] = f.y;
      T[r][c0 + i * 4 + 2] = f.z;
      T[r][c0 + i * 4 + 3] = f.w;
    }
  }
  __syncthreads();
  int j = tid >> 2, p = tid & 3;
  int n = h * 64 + j;
  int kloc = p * 16;
  unsigned short hi[16], lo[16];
#pragma unroll
  for (int i = 0; i < 16; ++i) splitbf(T[kloc + i][j], hi[i], lo[i]);
  int kglob = kb * 64 + kloc;
  int col = (kglob >> 5) * 64 + (kglob & 31);
  uint4 uh, ul;
  uh.x = (unsigned)hi[0] | ((unsigned)hi[1] << 16);
  uh.y = (unsigned)hi[2] | ((unsigned)hi[3] << 16);
  uh.z = (unsigned)hi[4] | ((unsigned)hi[5] << 16);
  uh.w = (unsigned)hi[6] | ((unsigned)hi[7] << 16);
  *(uint4*)(D + (size_t)n * 2048 + col) = uh;
  uh.x = (unsigned)hi[8] | ((unsigned)hi[9] << 16);
  uh.y = (unsigned)hi[10] | ((unsigned)hi[11] << 16);
  uh.z = (unsigned)hi[12] | ((unsigned)hi[13] << 16);
  uh.w = (unsigned)hi[14] | ((unsigned)hi[15] << 16);
  *(uint4*)(D + (size_t)n * 2048 + col + 8) = uh;
  ul.x = (unsigned)lo[0] | ((unsigned)lo[1] << 16);
  ul.y = (unsigned)lo[2] | ((unsigned)lo[3] << 16);
  ul.z = (unsigned)lo[4] | ((unsigned)lo[5] << 16);
  ul.w = (unsigned)lo[6] | ((unsigned)lo[7] << 16);
  *(uint4*)(D + (size_t)n * 2048 + col + 32) = ul;
  ul.x = (unsigned)lo[8] | ((unsigned)lo[9] << 16);
  ul.y = (unsigned)lo[10] | ((unsigned)lo[11] << 16);
  ul.z = (unsigned)lo[12] | ((unsigned)lo[13] << 16);
  ul.w = (unsigned)lo[14] | ((unsigned)lo[15] << 16);
  *(uint4*)(D + (size_t)n * 2048 + col + 40) = ul;
}

// ---------------------------------------------------------------------------
// Pipelined split-MFMA projection GEMM. 128x128 tile, BK=32.
// A fp32: reg-prefetch (issued after B1, drained at B2 behind MFMAs).
// B packed bf16: global_load_lds into double-buffered LDS half.
// grid (8 ntile, 32 mt, 3 z) = 768 blocks; LDS 48 KB -> 3 blocks/CU.
// ---------------------------------------------------------------------------
__global__ __launch_bounds__(256)
void proj_gemm(const float* __restrict__ Qin, const float* __restrict__ Kin,
               const float* __restrict__ Vin,
               const unsigned short* __restrict__ Wqt,
               const unsigned short* __restrict__ Wkt,
               const unsigned short* __restrict__ Wvt,
               const float* __restrict__ bq, const float* __restrict__ bk,
               const float* __restrict__ bv, unsigned short* __restrict__ q_all,
               unsigned short* __restrict__ k_all,
               unsigned short* __restrict__ vt) {
  const int ntile = blockIdx.x, mt = blockIdx.y, z = blockIdx.z;
  const float* A = (z == 0 ? Qin : z == 1 ? Kin : Vin);
  const unsigned short* B = (z == 0 ? Wqt : z == 1 ? Wkt : Wvt);
  const float* bias = (z == 0 ? bq : z == 1 ? bk : bv);

  __shared__ alignas(16) unsigned short As[128 * 64];
  __shared__ alignas(16) unsigned short Bs[2][128 * 64];

  const int tid = threadIdx.x;
  const int lane = tid & 63, w = tid >> 6;
  const int l15 = lane & 15, quad = lane >> 4;
  const int wm = (w & 1) * 64, wn = (w >> 1) * 64;

  const float* Ap = A + (size_t)(mt * 128) * DM;
  const unsigned short* Bp = B + (size_t)(ntile * 128) * 2048;

  // prologue: A regs for k=0, B glds for k=0
  float4 areg[4];
#pragma unroll
  for (int it = 0; it < 4; ++it) {
    int c = tid + it * 256;
    int r = c >> 3, seg = c & 7;
    areg[it] = *(const float4*)(Ap + (size_t)r * DM + seg * 4);
  }
#pragma unroll
  for (int it = 0; it < 4; ++it) {
    int s = tid + it * 256;
    int r = s >> 3, seg = s & 7;
    gld16(Bp + (size_t)r * 2048 + seg * 8, &Bs[0][s * 8]);
  }

  f32x4 acc[4][4];
#pragma unroll
  for (int i = 0; i < 4; ++i)
#pragma unroll
    for (int j = 0; j < 4; ++j) acc[i][j] = (f32x4){0.f, 0.f, 0.f, 0.f};

  int cur = 0;
  for (int kk = 0; kk < 32; ++kk) {
    // write As(k) from regs (split)
#pragma unroll
    for (int it = 0; it < 4; ++it) {
      int c = tid + it * 256;
      int r = c >> 3, seg = c & 7;
      ushort4 h4, l4;
      splitbf(areg[it].x, h4.x, l4.x);
      splitbf(areg[it].y, h4.y, l4.y);
      splitbf(areg[it].z, h4.z, l4.z);
      splitbf(areg[it].w, h4.w, l4.w);
      *(ushort4*)&As[r * 64 + seg * 4] = h4;
      *(ushort4*)&As[r * 64 + 32 + seg * 4] = l4;
    }
    __syncthreads();  // B1: cheap (only LDS writes outstanding)

    // prefetch k+1 (drained at B2, behind the MFMA section)
    if (kk + 1 < 32) {
      int k0n = (kk + 1) * 32;
#pragma unroll
      for (int it = 0; it < 4; ++it) {
        int c = tid + it * 256;
        int r = c >> 3, seg = c & 7;
        areg[it] = *(const float4*)(Ap + (size_t)r * DM + k0n + seg * 4);
      }
#pragma unroll
      for (int it = 0; it < 4; ++it) {
        int s = tid + it * 256;
        int r = s >> 3, seg = s & 7;
        gld16(Bp + (size_t)r * 2048 + (k0n >> 5) * 64 + seg * 8,
              &Bs[cur ^ 1][s * 8]);
      }
    }

    // compute on As, Bs[cur]
    bf16x8 ah[4], al[4];
#pragma unroll
    for (int i = 0; i < 4; ++i) {
      const unsigned short* p = &As[(wm + i * 16 + l15) * 64 + quad * 8];
      ah[i] = *(const bf16x8*)(p);
      al[i] = *(const bf16x8*)(p + 32);
    }
#pragma unroll
    for (int j = 0; j < 4; ++j) {
      const unsigned short* p = &Bs[cur][(wn + j * 16 + l15) * 64 + quad * 8];
      bf16x8 bh = *(const bf16x8*)(p);
      bf16x8 bl = *(const bf16x8*)(p + 32);
#pragma unroll
      for (int i = 0; i < 4; ++i) {
        acc[i][j] = __builtin_amdgcn_mfma_f32_16x16x32_bf16(ah[i], bh, acc[i][j], 0, 0, 0);
        acc[i][j] = __builtin_amdgcn_mfma_f32_16x16x32_bf16(al[i], bh, acc[i][j], 0, 0, 0);
        acc[i][j] = __builtin_amdgcn_mfma_f32_16x16x32_bf16(ah[i], bl, acc[i][j], 0, 0, 0);
      }
    }
    __syncthreads();  // B2: drains prefetches (overlapped) + LDS reads
    cur ^= 1;
  }

  if (z <= 1) {
    unsigned short* dst = (z == 0 ? q_all : k_all);
#pragma unroll
    for (int i = 0; i < 4; ++i)
#pragma unroll
      for (int j = 0; j < 4; ++j) {
        int n = ntile * 128 + wn + j * 16 + l15;
        int col = (n >> 5) * 64 + (n & 31);
        float bn = bias[n];
#pragma unroll
        for (int r = 0; r < 4; ++r) {
          int m = mt * 128 + wm + i * 16 + quad * 4 + r;
          unsigned short hh, ll;
          splitbf(acc[i][j][r] + bn, hh, ll);
          dst[(size_t)m * 2048 + col] = hh;
          dst[(size_t)m * 2048 + col + 32] = ll;
        }
      }
  } else {
    // vt layout: [b*NH+h][d 0..63][hi 2048 s | lo 2048 s]
#pragma unroll
    for (int i = 0; i < 4; ++i)
#pragma unroll
      for (int j = 0; j < 4; ++j) {
        int n = ntile * 128 + wn + j * 16 + l15;
        int h = n >> 6, d = n & 63;
        float bn = bias[n];
        int m0 = mt * 128 + wm + i * 16 + quad * 4;
        int b = m0 >> 11, s = m0 & 2047;
        ushort4 h4, l4;
        splitbf(acc[i][j][0] + bn, h4.x, l4.x);
        splitbf(acc[i][j][1] + bn, h4.y, l4.y);
        splitbf(acc[i][j][2] + bn, h4.z, l4.z);
        splitbf(acc[i][j][3] + bn, h4.w, l4.w);
        size_t base = (size_t)(b * NH + h) * (64 * 4096) + (size_t)d * 4096 + s;
        *(ushort4*)(vt + base) = h4;
        *(ushort4*)(vt + base + 2048) = l4;
      }
  }
}

// ---------------------------------------------------------------------------
// Pipelined output GEMM (mirror of proj): A = a_all packed (glds dbuf),
// B = Wo fp32 (reg-prefetch + split). grid (8 ntile, 32 mt).
// ---------------------------------------------------------------------------
__global__ __launch_bounds__(256)
void out_gemm(const unsigned short* __restrict__ a_all,
              const float* __restrict__ Wo, const float* __restrict__ bo,
              float* __restrict__ out) {
  const int ntile = blockIdx.x, mt = blockIdx.y;

  __shared__ alignas(16) unsigned short As[2][128 * 64];
  __shared__ alignas(16) unsigned short Bs[128 * 64];

  const int tid = threadIdx.x;
  const int lane = tid & 63, w = tid >> 6;
  const int l15 = lane & 15, quad = lane >> 4;
  const int wm = (w & 1) * 64, wn = (w >> 1) * 64;

  const unsigned short* Ap = a_all + (size_t)(mt * 128) * 2048;
  const float* Bp = Wo + (size_t)(ntile * 128) * DM;

  float4 breg[4];
#pragma unroll
  for (int it = 0; it < 4; ++it) {
    int c = tid + it * 256;
    int r = c >> 3, seg = c & 7;
    breg[it] = *(const float4*)(Bp + (size_t)r * DM + seg * 4);
  }
#pragma unroll
  for (int it = 0; it < 4; ++it) {
    int s = tid + it * 256;
    int r = s >> 3, seg = s & 7;
    gld16(Ap + (size_t)r * 2048 + seg * 8, &As[0][s * 8]);
  }

  f32x4 acc[4][4];
#pragma unroll
  for (int i = 0; i < 4; ++i)
#pragma unroll
    for (int j = 0; j < 4; ++j) acc[i][j] = (f32x4){0.f, 0.f, 0.f, 0.f};

  int cur = 0;
  for (int kk = 0; kk < 32; ++kk) {
#pragma unroll
    for (int it = 0; it < 4; ++it) {
      int c = tid + it * 256;
      int r = c >> 3, seg = c & 7;
      ushort4 h4, l4;
      splitbf(breg[it].x, h4.x, l4.x);
      splitbf(breg[it].y, h4.y, l4.y);
      splitbf(breg[it].z, h4.z, l4.z);
      splitbf(breg[it].w, h4.w, l4.w);
      *(ushort4*)&Bs[r * 64 + seg * 4] = h4;
      *(ushort4*)&Bs[r * 64 + 32 + seg * 4] = l4;
    }
    __syncthreads();

    if (kk + 1 < 32) {
      int k0n = (kk + 1) * 32;
#pragma unroll
      for (int it = 0; it < 4; ++it) {
        int c = tid + it * 256;
        int r = c >> 3, seg = c & 7;
        breg[it] = *(const float4*)(Bp + (size_t)r * DM + k0n + seg * 4);
      }
#pragma unroll
      for (int it = 0; it < 4; ++it) {
        int s = tid + it * 256;
        int r = s >> 3, seg = s & 7;
        gld16(Ap + (size_t)r * 2048 + (k0n >> 5) * 64 + seg * 8,
              &As[cur ^ 1][s * 8]);
      }
    }

    bf16x8 ah[4], al[4];
#pragma unroll
    for (int i = 0; i < 4; ++i) {
      const unsigned short* p = &As[cur][(wm + i * 16 + l15) * 64 + quad * 8];
      ah[i] = *(const bf16x8*)(p);
      al[i] = *(const bf16x8*)(p + 32);
    }
#pragma unroll
    for (int j = 0; j < 4; ++j) {
      const unsigned short* p = &Bs[(wn + j * 16 + l15) * 64 + quad * 8];
      bf16x8 bh = *(const bf16x8*)(p);
      bf16x8 bl = *(const bf16x8*)(p + 32);
#pragma unroll
      for (int i = 0; i < 4; ++i) {
        acc[i][j] = __builtin_amdgcn_mfma_f32_16x16x32_bf16(ah[i], bh, acc[i][j], 0, 0, 0);
        acc[i][j] = __builtin_amdgcn_mfma_f32_16x16x32_bf16(al[i], bh, acc[i][j], 0, 0, 0);
        acc[i][j] = __builtin_amdgcn_mfma_f32_16x16x32_bf16(ah[i], bl, acc[i][j], 0, 0, 0);
      }
    }
    __syncthreads();
    cur ^= 1;
  }

#pragma unroll
  for (int i = 0; i < 4; ++i)
#pragma unroll
    for (int j = 0; j < 4; ++j) {
      int n = ntile * 128 + wn + j * 16 + l15;
      float bn = bo[n];
#pragma unroll
      for (int r = 0; r < 4; ++r) {
        int m = mt * 128 + wm + i * 16 + quad * 4 + r;
        out[(size_t)m * DM + n] = acc[i][j][r] + bn;
      }
    }
}

// ---------------------------------------------------------------------------
// MFMA flash attention; K/V staged via global_load_lds (unpadded LDS).
// K LDS row: [kb0 hi32|lo32][kb1 hi32|lo32]; V LDS row d: [hi s0..63|lo s0..63].
// ---------------------------------------------------------------------------
#define LDP 72

__global__ __launch_bounds__(256)
void attn_kernel(const unsigned short* __restrict__ q_all,
                 const unsigned short* __restrict__ k_all,
                 const unsigned short* __restrict__ vt,
                 unsigned short* __restrict__ a_all) {
  const int qt = blockIdx.x, h = blockIdx.y, b = blockIdx.z;
  const unsigned short* vp = vt + (size_t)(b * NH + h) * (64 * 4096);

  __shared__ alignas(16) unsigned short Ks[64 * 128];
  __shared__ alignas(16) unsigned short Vs[64 * 128];
  __shared__ alignas(16) unsigned short Ps[64 * LDP];

  const int tid = threadIdx.x;
  const int lane = tid & 63;
  const int w = tid >> 6;
  const int l15 = lane & 15;
  const int quad = lane >> 4;

  bf16x8 qf[2][2];
  {
    const unsigned short* qrow =
        q_all + (size_t)(b * SLEN + qt * 64 + w * 16 + l15) * 2048;
#pragma unroll
    for (int kb = 0; kb < 2; ++kb) {
      qf[kb][0] = *(const bf16x8*)(qrow + (2 * h + kb) * 64 + quad * 8);
      qf[kb][1] = *(const bf16x8*)(qrow + (2 * h + kb) * 64 + 32 + quad * 8);
    }
  }

  f32x4 o[4];
#pragma unroll
  for (int nt = 0; nt < 4; ++nt) o[nt] = (f32x4){0.f, 0.f, 0.f, 0.f};
  float lpart[4] = {0.f, 0.f, 0.f, 0.f};

  for (int kt = 0; kt < STILES; ++kt) {
    // K: rows kt*64.., per-head 128-u16 slice (identity copy)
    const unsigned short* ksrc =
        k_all + (size_t)(b * SLEN + kt * 64) * 2048 + 2 * h * 64;
#pragma unroll
    for (int it = 0; it < 4; ++it) {
      int s = it * 256 + tid;
      int r = s >> 4, seg = s & 15;
      gld16(ksrc + (size_t)r * 2048 + seg * 8, &Ks[s * 8]);
    }
    // V: row d: hi half at d*4096 + kt*64, lo half at +2048
#pragma unroll
    for (int it = 0; it < 4; ++it) {
      int s = it * 256 + tid;
      int d = s >> 4, ws_ = s & 15;
      int half = ws_ >> 3, sc = (ws_ & 7) * 8;
      gld16(vp + (size_t)d * 4096 + half * 2048 + kt * 64 + sc, &Vs[s * 8]);
    }
    __syncthreads();

    f32x4 s[4];
#pragma unroll
    for (int ct = 0; ct < 4; ++ct) s[ct] = (f32x4){0.f, 0.f, 0.f, 0.f};
#pragma unroll
    for (int ct = 0; ct < 4; ++ct) {
#pragma unroll
      for (int kb = 0; kb < 2; ++kb) {
        const unsigned short* krow =
            &Ks[(ct * 16 + l15) * 128 + kb * 64 + quad * 8];
        bf16x8 kh = *(const bf16x8*)(krow);
        bf16x8 kl = *(const bf16x8*)(krow + 32);
        s[ct] = __builtin_amdgcn_mfma_f32_16x16x32_bf16(qf[kb][0], kh, s[ct], 0, 0, 0);
        s[ct] = __builtin_amdgcn_mfma_f32_16x16x32_bf16(qf[kb][0], kl, s[ct], 0, 0, 0);
        s[ct] = __builtin_amdgcn_mfma_f32_16x16x32_bf16(qf[kb][1], kh, s[ct], 0, 0, 0);
      }
    }

#pragma unroll
    for (int ct = 0; ct < 4; ++ct) {
#pragma unroll
      for (int r = 0; r < 4; ++r) {
        float e = __expf(s[ct][r] * 0.125f);
        lpart[r] += e;
        Ps[(w * 16 + quad * 4 + r) * LDP + ct * 16 + l15] = f2bf(e);
      }
    }
    __syncthreads();

#pragma unroll
    for (int kb = 0; kb < 2; ++kb) {
      bf16x8 pf = *(const bf16x8*)(&Ps[(w * 16 + l15) * LDP + kb * 32 + quad * 8]);
#pragma unroll
      for (int nt = 0; nt < 4; ++nt) {
        const unsigned short* vrow =
            &Vs[(nt * 16 + l15) * 128 + kb * 32 + quad * 8];
        bf16x8 vh = *(const bf16x8*)(vrow);
        bf16x8 vl = *(const bf16x8*)(vrow + 64);
        o[nt] = __builtin_amdgcn_mfma_f32_16x16x32_bf16(pf, vh, o[nt], 0, 0, 0);
        o[nt] = __builtin_amdgcn_mfma_f32_16x16x32_bf16(pf, vl, o[nt], 0, 0, 0);
      }
    }
    __syncthreads();
  }

  float inv[4];
#pragma unroll
  for (int r = 0; r < 4; ++r) {
    float lv = lpart[r];
#pragma unroll
    for (int m = 1; m < 16; m <<= 1) lv += __shfl_xor(lv, m, 64);
    inv[r] = 1.f / lv;
  }
#pragma unroll
  for (int nt = 0; nt < 4; ++nt) {
    int c = h * 64 + nt * 16 + l15;
    int pc = (c >> 5) * 64 + (c & 31);
#pragma unroll
    for (int r = 0; r < 4; ++r) {
      float val = o[nt][r] * inv[r];
      int row = qt * 64 + w * 16 + quad * 4 + r;
      size_t g = (size_t)(b * SLEN + row) * 2048 + pc;
      unsigned short hh, ll;
      splitbf(val, hh, ll);
      a_all[g] = hh;
      a_all[g + 32] = ll;
    }
  }
}

extern "C" void kernel_launch(void* const* d_in, const int* in_sizes, int n_in,
                              void* d_out, int out_size, void* d_ws,
                              size_t ws_size, hipStream_t stream) {
  (void)in_sizes; (void)n_in; (void)out_size; (void)ws_size;
  const float* Q = (const float*)d_in[0];
  const float* K = (const float*)d_in[1];
  const float* V = (const float*)d_in[2];
  const float* Wq = (const float*)d_in[3];
  const float* bq = (const float*)d_in[4];
  const float* Wk = (const float*)d_in[5];
  const float* bk = (const float*)d_in[6];
  const float* Wv = (const float*)d_in[7];
  const float* bv = (const float*)d_in[8];
  const float* Wo = (const float*)d_in[9];
  const float* bo = (const float*)d_in[10];
  float* out = (float*)d_out;

  unsigned short* us = (unsigned short*)d_ws;
  const size_t M8 = 8u * 1024 * 1024;
  unsigned short* q_all = us;
  unsigned short* k_all = us + M8;
  unsigned short* vt = us + 2 * M8;
  unsigned short* a_all = us + 3 * M8;
  unsigned short* Wqt = a_all;  // dead by the time attn writes a_all
  unsigned short* Wkt = a_all + 2 * 1024 * 1024;
  unsigned short* Wvt = a_all + 4 * 1024 * 1024;

  convert_w<<<dim3(16, 16, 3), 256, 0, stream>>>(Wq, Wk, Wv, Wqt, Wkt, Wvt);
  proj_gemm<<<dim3(8, 32, 3), 256, 0, stream>>>(Q, K, V, Wqt, Wkt, Wvt, bq,
                                                bk, bv, q_all, k_all, vt);
  attn_kernel<<<dim3(STILES, NH, BATCH), 256, 0, stream>>>(q_all, k_all, vt,
                                                           a_all);
  out_gemm<<<dim3(8, 32), 256, 0, stream>>>(a_all, Wo, bo, out);
}

// Round 6
// 388.569 us; speedup vs baseline: 1.6529x; 1.4643x over previous
//
#include <hip/hip_runtime.h>
#include <math.h>

#define BATCH 2
#define SLEN 2048
#define DM 1024
#define NH 16
#define DK 64
#define STILES (SLEN / 64)  // 32

typedef __attribute__((ext_vector_type(8))) __bf16 bf16x8;
typedef __attribute__((ext_vector_type(4))) float f32x4;

__device__ __forceinline__ unsigned short f2bf(float x) {  // round-nearest
  unsigned u = __builtin_bit_cast(unsigned, x);
  unsigned r = (u + 0x7fffu + ((u >> 16) & 1u)) >> 16;
  return (unsigned short)r;
}
__device__ __forceinline__ float bf2f(unsigned short b) {
  unsigned u = ((unsigned)b) << 16;
  return __builtin_bit_cast(float, u);
}
// cheap truncation split: x ~= hi + lo to ~2^-16 relative
__device__ __forceinline__ void splitbf(float x, unsigned short& h,
                                        unsigned short& l) {
  unsigned u = __builtin_bit_cast(unsigned, x);
  h = (unsigned short)(u >> 16);
  float hf = __builtin_bit_cast(float, u & 0xffff0000u);
  l = (unsigned short)(__builtin_bit_cast(unsigned, x - hf) >> 16);
}

// async global->LDS, 16 B per lane
__device__ __forceinline__ void gld16(const unsigned short* g,
                                      unsigned short* l) {
  __builtin_amdgcn_global_load_lds(
      (const __attribute__((address_space(1))) void*)g,
      (__attribute__((address_space(3))) void*)l, 16, 0, 0);
}

// ---------------------------------------------------------------------------
// Weight transpose+split -> Wt[n][packed k], 64-u16 k-blocks [hi32|lo32],
// 16-B chunks XOR-swizzled with key (n&7) so proj's glds staging + fragment
// reads are bank-balanced.
// ---------------------------------------------------------------------------
__global__ __launch_bounds__(256)
void convert_w(const float* __restrict__ Wq, const float* __restrict__ Wk,
               const float* __restrict__ Wv, unsigned short* __restrict__ Wqt,
               unsigned short* __restrict__ Wkt,
               unsigned short* __restrict__ Wvt) {
  const int kb = blockIdx.x, h = blockIdx.y, z = blockIdx.z;
  const float* W = (z == 0 ? Wq : z == 1 ? Wk : Wv) +
                   ((size_t)h * DM + kb * 64) * DK;
  unsigned short* D = (z == 0 ? Wqt : z == 1 ? Wkt : Wvt);

  __shared__ float T[64][65];
  const int tid = threadIdx.x;
  {
    int r = tid >> 2, c0 = (tid & 3) * 16;
#pragma unroll
    for (int i = 0; i < 4; ++i) {
      float4 f = *(const float4*)(W + (size_t)r * DK + c0 + i * 4);
      T[r][c0 + i * 4 + 0] = f.x;
      T[r][c0 + i * 4 + 1] = f.y;
      T[r][c0 + i * 4 + 2] = f.z;
      T[r][c0 + i * 4 + 3] = f.w;
    }
  }
  __syncthreads();
  int j = tid >> 2, p = tid & 3;
  int n = h * 64 + j;
  int kloc = p * 16;
  unsigned short hi[16], lo[16];
#pragma unroll
  for (int i = 0; i < 16; ++i) splitbf(T[kloc + i][j], hi[i], lo[i]);
  int kglob = kb * 64 + kloc;
  int blk = kglob >> 5;          // 64-u16 block
  int c0 = (kglob & 31) >> 3;    // 0 or 2
  int key = n & 7;
  unsigned short* rowp = D + (size_t)n * 2048 + blk * 64;
  uint4 u0, u1;
  u0.x = (unsigned)hi[0] | ((unsigned)hi[1] << 16);
  u0.y = (unsigned)hi[2] | ((unsigned)hi[3] << 16);
  u0.z = (unsigned)hi[4] | ((unsigned)hi[5] << 16);
  u0.w = (unsigned)hi[6] | ((unsigned)hi[7] << 16);
  u1.x = (unsigned)hi[8] | ((unsigned)hi[9] << 16);
  u1.y = (unsigned)hi[10] | ((unsigned)hi[11] << 16);
  u1.z = (unsigned)hi[12] | ((unsigned)hi[13] << 16);
  u1.w = (unsigned)hi[14] | ((unsigned)hi[15] << 16);
  *(uint4*)(rowp + ((c0 ^ key)) * 8) = u0;
  *(uint4*)(rowp + (((c0 + 1) ^ key)) * 8) = u1;
  u0.x = (unsigned)lo[0] | ((unsigned)lo[1] << 16);
  u0.y = (unsigned)lo[2] | ((unsigned)lo[3] << 16);
  u0.z = (unsigned)lo[4] | ((unsigned)lo[5] << 16);
  u0.w = (unsigned)lo[6] | ((unsigned)lo[7] << 16);
  u1.x = (unsigned)lo[8] | ((unsigned)lo[9] << 16);
  u1.y = (unsigned)lo[10] | ((unsigned)lo[11] << 16);
  u1.z = (unsigned)lo[12] | ((unsigned)lo[13] << 16);
  u1.w = (unsigned)lo[14] | ((unsigned)lo[15] << 16);
  *(uint4*)(rowp + (((c0 + 4) ^ key)) * 8) = u0;
  *(uint4*)(rowp + (((c0 + 5) ^ key)) * 8) = u1;
}

// ---------------------------------------------------------------------------
// Pipelined split-MFMA projection GEMM, swizzled LDS. 128x128 tile, BK=32.
// ---------------------------------------------------------------------------
__global__ __launch_bounds__(256)
void proj_gemm(const float* __restrict__ Qin, const float* __restrict__ Kin,
               const float* __restrict__ Vin,
               const unsigned short* __restrict__ Wqt,
               const unsigned short* __restrict__ Wkt,
               const unsigned short* __restrict__ Wvt,
               const float* __restrict__ bq, const float* __restrict__ bk,
               const float* __restrict__ bv, unsigned short* __restrict__ q_all,
               unsigned short* __restrict__ k_all,
               unsigned short* __restrict__ vt) {
  const int ntile = blockIdx.x, mt = blockIdx.y, z = blockIdx.z;
  const float* A = (z == 0 ? Qin : z == 1 ? Kin : Vin);
  const unsigned short* B = (z == 0 ? Wqt : z == 1 ? Wkt : Wvt);
  const float* bias = (z == 0 ? bq : z == 1 ? bk : bv);

  __shared__ alignas(16) unsigned short As[128 * 64];
  __shared__ alignas(16) unsigned short Bs[2][128 * 64];

  const int tid = threadIdx.x;
  const int lane = tid & 63, w = tid >> 6;
  const int l15 = lane & 15, quad = lane >> 4;
  const int wm = (w & 1) * 64, wn = (w >> 1) * 64;
  const int kx = l15 & 7;

  const float* Ap = A + (size_t)(mt * 128) * DM;
  const unsigned short* Bp = B + (size_t)(ntile * 128) * 2048;

  float4 areg[4];
#pragma unroll
  for (int it = 0; it < 4; ++it) {
    int c = tid + it * 256;
    int r = c >> 3, seg = c & 7;
    areg[it] = *(const float4*)(Ap + (size_t)r * DM + seg * 4);
  }
#pragma unroll
  for (int it = 0; it < 4; ++it) {
    int s = tid + it * 256;
    int r = s >> 3, seg = s & 7;
    gld16(Bp + (size_t)r * 2048 + seg * 8, &Bs[0][s * 8]);
  }

  f32x4 acc[4][4];
#pragma unroll
  for (int i = 0; i < 4; ++i)
#pragma unroll
    for (int j = 0; j < 4; ++j) acc[i][j] = (f32x4){0.f, 0.f, 0.f, 0.f};

  int cur = 0;
  for (int kk = 0; kk < 32; ++kk) {
#pragma unroll
    for (int it = 0; it < 4; ++it) {
      int c = tid + it * 256;
      int r = c >> 3, seg = c & 7;
      int key = r & 7, ch = seg >> 1, off = (seg & 1) * 4;
      ushort4 h4, l4;
      splitbf(areg[it].x, h4.x, l4.x);
      splitbf(areg[it].y, h4.y, l4.y);
      splitbf(areg[it].z, h4.z, l4.z);
      splitbf(areg[it].w, h4.w, l4.w);
      *(ushort4*)&As[r * 64 + ((ch ^ key)) * 8 + off] = h4;
      *(ushort4*)&As[r * 64 + (((ch + 4) ^ key)) * 8 + off] = l4;
    }
    __syncthreads();  // B1

    if (kk + 1 < 32) {
      int k0n = (kk + 1) * 32;
#pragma unroll
      for (int it = 0; it < 4; ++it) {
        int c = tid + it * 256;
        int r = c >> 3, seg = c & 7;
        areg[it] = *(const float4*)(Ap + (size_t)r * DM + k0n + seg * 4);
      }
#pragma unroll
      for (int it = 0; it < 4; ++it) {
        int s = tid + it * 256;
        int r = s >> 3, seg = s & 7;
        gld16(Bp + (size_t)r * 2048 + (k0n >> 5) * 64 + seg * 8,
              &Bs[cur ^ 1][s * 8]);
      }
    }

    bf16x8 ah[4], al[4];
#pragma unroll
    for (int i = 0; i < 4; ++i) {
      const unsigned short* p = &As[(wm + i * 16 + l15) * 64];
      ah[i] = *(const bf16x8*)(p + ((quad ^ kx)) * 8);
      al[i] = *(const bf16x8*)(p + (((quad + 4) ^ kx)) * 8);
    }
#pragma unroll
    for (int j = 0; j < 4; ++j) {
      const unsigned short* p = &Bs[cur][(wn + j * 16 + l15) * 64];
      bf16x8 bh = *(const bf16x8*)(p + ((quad ^ kx)) * 8);
      bf16x8 bl = *(const bf16x8*)(p + (((quad + 4) ^ kx)) * 8);
#pragma unroll
      for (int i = 0; i < 4; ++i) {
        acc[i][j] = __builtin_amdgcn_mfma_f32_16x16x32_bf16(ah[i], bh, acc[i][j], 0, 0, 0);
        acc[i][j] = __builtin_amdgcn_mfma_f32_16x16x32_bf16(al[i], bh, acc[i][j], 0, 0, 0);
        acc[i][j] = __builtin_amdgcn_mfma_f32_16x16x32_bf16(ah[i], bl, acc[i][j], 0, 0, 0);
      }
    }
    __syncthreads();  // B2
    cur ^= 1;
  }

  if (z <= 1) {
    // q_all/k_all: per-head 128-u16 slices, 16-chunk swizzle key (m&15)
    unsigned short* dst = (z == 0 ? q_all : k_all);
#pragma unroll
    for (int i = 0; i < 4; ++i)
#pragma unroll
      for (int j = 0; j < 4; ++j) {
        int n = ntile * 128 + wn + j * 16 + l15;
        int hh_ = n >> 6, d = n & 63;
        int chi = (d >> 5) * 8 + ((d & 31) >> 3);
        float bn = bias[n];
#pragma unroll
        for (int r = 0; r < 4; ++r) {
          int m = mt * 128 + wm + i * 16 + quad * 4 + r;
          int key = m & 15;
          size_t rb = (size_t)m * 2048 + hh_ * 128;
          unsigned short hv, lv;
          splitbf(acc[i][j][r] + bn, hv, lv);
          dst[rb + ((chi ^ key)) * 8 + (d & 7)] = hv;
          dst[rb + (((chi + 4) ^ key)) * 8 + (d & 7)] = lv;
        }
      }
  } else {
    // vt: [head][d][kt][16 chunks ^ (d&15)][8]
#pragma unroll
    for (int i = 0; i < 4; ++i)
#pragma unroll
      for (int j = 0; j < 4; ++j) {
        int n = ntile * 128 + wn + j * 16 + l15;
        int h = n >> 6, d = n & 63;
        float bn = bias[n];
        int m0 = mt * 128 + wm + i * 16 + quad * 4;
        int b = m0 >> 11, s0_ = m0 & 2047;
        int kt = s0_ >> 6, sl = s0_ & 63;
        int ch = sl >> 3, off = sl & 7, key = d & 15;
        ushort4 h4, l4;
        splitbf(acc[i][j][0] + bn, h4.x, l4.x);
        splitbf(acc[i][j][1] + bn, h4.y, l4.y);
        splitbf(acc[i][j][2] + bn, h4.z, l4.z);
        splitbf(acc[i][j][3] + bn, h4.w, l4.w);
        size_t base =
            (size_t)(b * NH + h) * 262144 + (size_t)d * 4096 + kt * 128;
        *(ushort4*)(vt + base + ((ch ^ key)) * 8 + off) = h4;
        *(ushort4*)(vt + base + (((ch + 8) ^ key)) * 8 + off) = l4;
      }
  }
}

// ---------------------------------------------------------------------------
// Pipelined output GEMM, swizzled LDS.
// ---------------------------------------------------------------------------
__global__ __launch_bounds__(256)
void out_gemm(const unsigned short* __restrict__ a_all,
              const float* __restrict__ Wo, const float* __restrict__ bo,
              float* __restrict__ out) {
  const int ntile = blockIdx.x, mt = blockIdx.y;

  __shared__ alignas(16) unsigned short As[2][128 * 64];
  __shared__ alignas(16) unsigned short Bs[128 * 64];

  const int tid = threadIdx.x;
  const int lane = tid & 63, w = tid >> 6;
  const int l15 = lane & 15, quad = lane >> 4;
  const int wm = (w & 1) * 64, wn = (w >> 1) * 64;
  const int kx = l15 & 7;

  const unsigned short* Ap = a_all + (size_t)(mt * 128) * 2048;
  const float* Bp = Wo + (size_t)(ntile * 128) * DM;

  float4 breg[4];
#pragma unroll
  for (int it = 0; it < 4; ++it) {
    int c = tid + it * 256;
    int r = c >> 3, seg = c & 7;
    breg[it] = *(const float4*)(Bp + (size_t)r * DM + seg * 4);
  }
#pragma unroll
  for (int it = 0; it < 4; ++it) {
    int s = tid + it * 256;
    int r = s >> 3, seg = s & 7;
    gld16(Ap + (size_t)r * 2048 + seg * 8, &As[0][s * 8]);
  }

  f32x4 acc[4][4];
#pragma unroll
  for (int i = 0; i < 4; ++i)
#pragma unroll
    for (int j = 0; j < 4; ++j) acc[i][j] = (f32x4){0.f, 0.f, 0.f, 0.f};

  int cur = 0;
  for (int kk = 0; kk < 32; ++kk) {
#pragma unroll
    for (int it = 0; it < 4; ++it) {
      int c = tid + it * 256;
      int r = c >> 3, seg = c & 7;
      int key = r & 7, ch = seg >> 1, off = (seg & 1) * 4;
      ushort4 h4, l4;
      splitbf(breg[it].x, h4.x, l4.x);
      splitbf(breg[it].y, h4.y, l4.y);
      splitbf(breg[it].z, h4.z, l4.z);
      splitbf(breg[it].w, h4.w, l4.w);
      *(ushort4*)&Bs[r * 64 + ((ch ^ key)) * 8 + off] = h4;
      *(ushort4*)&Bs[r * 64 + (((ch + 4) ^ key)) * 8 + off] = l4;
    }
    __syncthreads();

    if (kk + 1 < 32) {
      int k0n = (kk + 1) * 32;
#pragma unroll
      for (int it = 0; it < 4; ++it) {
        int c = tid + it * 256;
        int r = c >> 3, seg = c & 7;
        breg[it] = *(const float4*)(Bp + (size_t)r * DM + k0n + seg * 4);
      }
#pragma unroll
      for (int it = 0; it < 4; ++it) {
        int s = tid + it * 256;
        int r = s >> 3, seg = s & 7;
        gld16(Ap + (size_t)r * 2048 + (k0n >> 5) * 64 + seg * 8,
              &As[cur ^ 1][s * 8]);
      }
    }

    bf16x8 ah[4], al[4];
#pragma unroll
    for (int i = 0; i < 4; ++i) {
      const unsigned short* p = &As[cur][(wm + i * 16 + l15) * 64];
      ah[i] = *(const bf16x8*)(p + ((quad ^ kx)) * 8);
      al[i] = *(const bf16x8*)(p + (((quad + 4) ^ kx)) * 8);
    }
#pragma unroll
    for (int j = 0; j < 4; ++j) {
      const unsigned short* p = &Bs[(wn + j * 16 + l15) * 64];
      bf16x8 bh = *(const bf16x8*)(p + ((quad ^ kx)) * 8);
      bf16x8 bl = *(const bf16x8*)(p + (((quad + 4) ^ kx)) * 8);
#pragma unroll
      for (int i = 0; i < 4; ++i) {
        acc[i][j] = __builtin_amdgcn_mfma_f32_16x16x32_bf16(ah[i], bh, acc[i][j], 0, 0, 0);
        acc[i][j] = __builtin_amdgcn_mfma_f32_16x16x32_bf16(al[i], bh, acc[i][j], 0, 0, 0);
        acc[i][j] = __builtin_amdgcn_mfma_f32_16x16x32_bf16(ah[i], bl, acc[i][j], 0, 0, 0);
      }
    }
    __syncthreads();
    cur ^= 1;
  }

#pragma unroll
  for (int i = 0; i < 4; ++i)
#pragma unroll
    for (int j = 0; j < 4; ++j) {
      int n = ntile * 128 + wn + j * 16 + l15;
      float bn = bo[n];
#pragma unroll
      for (int r = 0; r < 4; ++r) {
        int m = mt * 128 + wm + i * 16 + quad * 4 + r;
        out[(size_t)m * DM + n] = acc[i][j][r] + bn;
      }
    }
}

// ---------------------------------------------------------------------------
// MFMA flash attention: block = 128 q-rows (4 waves x 32-row strips),
// swizzled K/V/P LDS, glds staging. grid (S/128, NH, B) = 512 blocks.
// ---------------------------------------------------------------------------
__global__ __launch_bounds__(256)
void attn_kernel(const unsigned short* __restrict__ q_all,
                 const unsigned short* __restrict__ k_all,
                 const unsigned short* __restrict__ vt,
                 unsigned short* __restrict__ a_all) {
  const int qt = blockIdx.x, h = blockIdx.y, b = blockIdx.z;
  const unsigned short* vp = vt + (size_t)(b * NH + h) * 262144;

  __shared__ alignas(16) unsigned short Ks[64 * 128];
  __shared__ alignas(16) unsigned short Vs[64 * 128];
  __shared__ alignas(16) unsigned short Ps[128 * 64];

  const int tid = threadIdx.x;
  const int lane = tid & 63;
  const int w = tid >> 6;
  const int l15 = lane & 15;
  const int quad = lane >> 4;

  // Q fragments (global, swizzle key = m&15 = l15): [rt][kb][hi/lo]
  bf16x8 qf[2][2][2];
#pragma unroll
  for (int rt = 0; rt < 2; ++rt) {
    const unsigned short* qrow =
        q_all + (size_t)(b * SLEN + qt * 128 + w * 32 + rt * 16 + l15) * 2048 +
        h * 128;
#pragma unroll
    for (int kb = 0; kb < 2; ++kb) {
      qf[rt][kb][0] = *(const bf16x8*)(qrow + ((kb * 8 + quad) ^ l15) * 8);
      qf[rt][kb][1] = *(const bf16x8*)(qrow + ((kb * 8 + quad + 4) ^ l15) * 8);
    }
  }

  f32x4 o[2][4];
  float lpart[2][4];
#pragma unroll
  for (int rt = 0; rt < 2; ++rt)
#pragma unroll
    for (int nt = 0; nt < 4; ++nt) {
      o[rt][nt] = (f32x4){0.f, 0.f, 0.f, 0.f};
      lpart[rt][nt] = 0.f;
    }

  for (int kt = 0; kt < STILES; ++kt) {
    const unsigned short* ksrc =
        k_all + (size_t)(b * SLEN + kt * 64) * 2048 + h * 128;
#pragma unroll
    for (int it = 0; it < 4; ++it) {
      int ss = it * 256 + tid;
      int r = ss >> 4, p = ss & 15;
      gld16(ksrc + (size_t)r * 2048 + p * 8, &Ks[ss * 8]);
    }
#pragma unroll
    for (int it = 0; it < 4; ++it) {
      int ss = it * 256 + tid;
      int d = ss >> 4, p = ss & 15;
      gld16(vp + (size_t)d * 4096 + kt * 128 + p * 8, &Vs[ss * 8]);
    }
    __syncthreads();

    // S = Q K^T (3-term split), per wave: 32 q-rows x 64 k-cols
    f32x4 sc[2][4];
#pragma unroll
    for (int rt = 0; rt < 2; ++rt)
#pragma unroll
      for (int ct = 0; ct < 4; ++ct) sc[rt][ct] = (f32x4){0.f, 0.f, 0.f, 0.f};
#pragma unroll
    for (int ct = 0; ct < 4; ++ct) {
      const unsigned short* kbase = &Ks[(ct * 16 + l15) * 128];
#pragma unroll
      for (int kb = 0; kb < 2; ++kb) {
        bf16x8 kh = *(const bf16x8*)(kbase + ((kb * 8 + quad) ^ l15) * 8);
        bf16x8 kl = *(const bf16x8*)(kbase + ((kb * 8 + quad + 4) ^ l15) * 8);
#pragma unroll
        for (int rt = 0; rt < 2; ++rt) {
          sc[rt][ct] = __builtin_amdgcn_mfma_f32_16x16x32_bf16(qf[rt][kb][0], kh, sc[rt][ct], 0, 0, 0);
          sc[rt][ct] = __builtin_amdgcn_mfma_f32_16x16x32_bf16(qf[rt][kb][0], kl, sc[rt][ct], 0, 0, 0);
          sc[rt][ct] = __builtin_amdgcn_mfma_f32_16x16x32_bf16(qf[rt][kb][1], kh, sc[rt][ct], 0, 0, 0);
        }
      }
    }

    // softmax numerator; P -> swizzled LDS (key = (row>>1)&7)
#pragma unroll
    for (int rt = 0; rt < 2; ++rt)
#pragma unroll
      for (int ct = 0; ct < 4; ++ct)
#pragma unroll
        for (int r = 0; r < 4; ++r) {
          float e = __expf(sc[rt][ct][r] * 0.125f);
          lpart[rt][r] += e;
          int prow = w * 32 + rt * 16 + quad * 4 + r;
          int pkey = (prow >> 1) & 7;
          Ps[prow * 64 + (((ct * 2 + (l15 >> 3)) ^ pkey)) * 8 + (l15 & 7)] =
              f2bf(e);
        }
    __syncthreads();

    // O += P V
    int rk = (l15 >> 1) & 7;
#pragma unroll
    for (int kb = 0; kb < 2; ++kb) {
      bf16x8 pf[2];
#pragma unroll
      for (int rt = 0; rt < 2; ++rt)
        pf[rt] = *(const bf16x8*)(&Ps[(w * 32 + rt * 16 + l15) * 64 +
                                      (((kb * 4 + quad) ^ rk)) * 8]);
#pragma unroll
      for (int nt = 0; nt < 4; ++nt) {
        const unsigned short* vb = &Vs[(nt * 16 + l15) * 128];
        bf16x8 vh = *(const bf16x8*)(vb + (((kb * 4 + quad) ^ l15)) * 8);
        bf16x8 vl = *(const bf16x8*)(vb + (((kb * 4 + quad + 8) ^ l15)) * 8);
#pragma unroll
        for (int rt = 0; rt < 2; ++rt) {
          o[rt][nt] = __builtin_amdgcn_mfma_f32_16x16x32_bf16(pf[rt], vh, o[rt][nt], 0, 0, 0);
          o[rt][nt] = __builtin_amdgcn_mfma_f32_16x16x32_bf16(pf[rt], vl, o[rt][nt], 0, 0, 0);
        }
      }
    }
    __syncthreads();
  }

  // epilogue: normalize, write a_all (8-chunk swizzle key m&7)
#pragma unroll
  for (int rt = 0; rt < 2; ++rt) {
    float inv[4];
#pragma unroll
    for (int r = 0; r < 4; ++r) {
      float lv = lpart[rt][r];
#pragma unroll
      for (int m = 1; m < 16; m <<= 1) lv += __shfl_xor(lv, m, 64);
      inv[r] = 1.f / lv;
    }
#pragma unroll
    for (int nt = 0; nt < 4; ++nt) {
      int c = h * 64 + nt * 16 + l15;
      int Bb = c >> 5;
      int d32 = c & 31;
      int ch = d32 >> 3, off = d32 & 7;
#pragma unroll
      for (int r = 0; r < 4; ++r) {
        float val = o[rt][nt][r] * inv[r];
        int srow = qt * 128 + w * 32 + rt * 16 + quad * 4 + r;
        int key = srow & 7;
        size_t g = (size_t)(b * SLEN + srow) * 2048 + Bb * 64;
        unsigned short hv, lv2;
        splitbf(val, hv, lv2);
        a_all[g + ((ch ^ key)) * 8 + off] = hv;
        a_all[g + (((ch + 4) ^ key)) * 8 + off] = lv2;
      }
    }
  }
}

extern "C" void kernel_launch(void* const* d_in, const int* in_sizes, int n_in,
                              void* d_out, int out_size, void* d_ws,
                              size_t ws_size, hipStream_t stream) {
  (void)in_sizes; (void)n_in; (void)out_size; (void)ws_size;
  const float* Q = (const float*)d_in[0];
  const float* K = (const float*)d_in[1];
  const float* V = (const float*)d_in[2];
  const float* Wq = (const float*)d_in[3];
  const float* bq = (const float*)d_in[4];
  const float* Wk = (const float*)d_in[5];
  const float* bk = (const float*)d_in[6];
  const float* Wv = (const float*)d_in[7];
  const float* bv = (const float*)d_in[8];
  const float* Wo = (const float*)d_in[9];
  const float* bo = (const float*)d_in[10];
  float* out = (float*)d_out;

  unsigned short* us = (unsigned short*)d_ws;
  const size_t M8 = 8u * 1024 * 1024;
  unsigned short* q_all = us;
  unsigned short* k_all = us + M8;
  unsigned short* vt = us + 2 * M8;
  unsigned short* a_all = us + 3 * M8;
  unsigned short* Wqt = a_all;  // dead by the time attn writes a_all
  unsigned short* Wkt = a_all + 2 * 1024 * 1024;
  unsigned short* Wvt = a_all + 4 * 1024 * 1024;

  convert_w<<<dim3(16, 16, 3), 256, 0, stream>>>(Wq, Wk, Wv, Wqt, Wkt, Wvt);
  proj_gemm<<<dim3(8, 32, 3), 256, 0, stream>>>(Q, K, V, Wqt, Wkt, Wvt, bq,
                                                bk, bv, q_all, k_all, vt);
  attn_kernel<<<dim3(SLEN / 128, NH, BATCH), 256, 0, stream>>>(q_all, k_all,
                                                               vt, a_all);
  out_gemm<<<dim3(8, 32), 256, 0, stream>>>(a_all, Wo, bo, out);
}

// Round 7
// 371.079 us; speedup vs baseline: 1.7308x; 1.0471x over previous
//
#include <hip/hip_runtime.h>
#include <math.h>

#define BATCH 2
#define SLEN 2048
#define DM 1024
#define NH 16
#define DK 64
#define STILES (SLEN / 64)  // 32

typedef __attribute__((ext_vector_type(8))) __bf16 bf16x8;
typedef __attribute__((ext_vector_type(4))) float f32x4;

__device__ __forceinline__ unsigned short f2bf(float x) {  // round-nearest
  unsigned u = __builtin_bit_cast(unsigned, x);
  unsigned r = (u + 0x7fffu + ((u >> 16) & 1u)) >> 16;
  return (unsigned short)r;
}
__device__ __forceinline__ float bf2f(unsigned short b) {
  unsigned u = ((unsigned)b) << 16;
  return __builtin_bit_cast(float, u);
}
// cheap truncation split: x ~= hi + lo to ~2^-16 relative
__device__ __forceinline__ void splitbf(float x, unsigned short& h,
                                        unsigned short& l) {
  unsigned u = __builtin_bit_cast(unsigned, x);
  h = (unsigned short)(u >> 16);
  float hf = __builtin_bit_cast(float, u & 0xffff0000u);
  l = (unsigned short)(__builtin_bit_cast(unsigned, x - hf) >> 16);
}

// async global->LDS, 16 B per lane
__device__ __forceinline__ void gld16(const unsigned short* g,
                                      unsigned short* l) {
  __builtin_amdgcn_global_load_lds(
      (const __attribute__((address_space(1))) void*)g,
      (__attribute__((address_space(3))) void*)l, 16, 0, 0);
}

// ---------------------------------------------------------------------------
// Weight transpose+split -> Wt[n][packed k], 64-u16 k-blocks [hi32|lo32],
// 16-B chunks XOR-swizzled with key (n&7).
// ---------------------------------------------------------------------------
__global__ __launch_bounds__(256)
void convert_w(const float* __restrict__ Wq, const float* __restrict__ Wk,
               const float* __restrict__ Wv, unsigned short* __restrict__ Wqt,
               unsigned short* __restrict__ Wkt,
               unsigned short* __restrict__ Wvt) {
  const int kb = blockIdx.x, h = blockIdx.y, z = blockIdx.z;
  const float* W = (z == 0 ? Wq : z == 1 ? Wk : Wv) +
                   ((size_t)h * DM + kb * 64) * DK;
  unsigned short* D = (z == 0 ? Wqt : z == 1 ? Wkt : Wvt);

  __shared__ float T[64][65];
  const int tid = threadIdx.x;
  {
    int r = tid >> 2, c0 = (tid & 3) * 16;
#pragma unroll
    for (int i = 0; i < 4; ++i) {
      float4 f = *(const float4*)(W + (size_t)r * DK + c0 + i * 4);
      T[r][c0 + i * 4 + 0] = f.x;
      T[r][c0 + i * 4 + 1] = f.y;
      T[r][c0 + i * 4 + 2] = f.z;
      T[r][c0 + i * 4 + 3] = f.w;
    }
  }
  __syncthreads();
  int j = tid >> 2, p = tid & 3;
  int n = h * 64 + j;
  int kloc = p * 16;
  unsigned short hi[16], lo[16];
#pragma unroll
  for (int i = 0; i < 16; ++i) splitbf(T[kloc + i][j], hi[i], lo[i]);
  int kglob = kb * 64 + kloc;
  int blk = kglob >> 5;
  int c0 = (kglob & 31) >> 3;
  int key = n & 7;
  unsigned short* rowp = D + (size_t)n * 2048 + blk * 64;
  uint4 u0, u1;
  u0.x = (unsigned)hi[0] | ((unsigned)hi[1] << 16);
  u0.y = (unsigned)hi[2] | ((unsigned)hi[3] << 16);
  u0.z = (unsigned)hi[4] | ((unsigned)hi[5] << 16);
  u0.w = (unsigned)hi[6] | ((unsigned)hi[7] << 16);
  u1.x = (unsigned)hi[8] | ((unsigned)hi[9] << 16);
  u1.y = (unsigned)hi[10] | ((unsigned)hi[11] << 16);
  u1.z = (unsigned)hi[12] | ((unsigned)hi[13] << 16);
  u1.w = (unsigned)hi[14] | ((unsigned)hi[15] << 16);
  *(uint4*)(rowp + ((c0 ^ key)) * 8) = u0;
  *(uint4*)(rowp + (((c0 + 1) ^ key)) * 8) = u1;
  u0.x = (unsigned)lo[0] | ((unsigned)lo[1] << 16);
  u0.y = (unsigned)lo[2] | ((unsigned)lo[3] << 16);
  u0.z = (unsigned)lo[4] | ((unsigned)lo[5] << 16);
  u0.w = (unsigned)lo[6] | ((unsigned)lo[7] << 16);
  u1.x = (unsigned)lo[8] | ((unsigned)lo[9] << 16);
  u1.y = (unsigned)lo[10] | ((unsigned)lo[11] << 16);
  u1.z = (unsigned)lo[12] | ((unsigned)lo[13] << 16);
  u1.w = (unsigned)lo[14] | ((unsigned)lo[15] << 16);
  *(uint4*)(rowp + (((c0 + 4) ^ key)) * 8) = u0;
  *(uint4*)(rowp + (((c0 + 5) ^ key)) * 8) = u1;
}

// ---------------------------------------------------------------------------
// Wo pre-split: Wo[n][k] fp32 -> Wot[n][packed k] (swizzled like Wt).
// Runs AFTER attn (q_all region is dead then). grid 1024, block 256.
// ---------------------------------------------------------------------------
__global__ __launch_bounds__(256)
void convert_wo(const float* __restrict__ Wo, unsigned short* __restrict__ Wot) {
  const int n = blockIdx.x;
  const int t = threadIdx.x;
  const int k0 = t * 4;
  float4 f = *(const float4*)(Wo + (size_t)n * DM + k0);
  ushort4 h4, l4;
  splitbf(f.x, h4.x, l4.x);
  splitbf(f.y, h4.y, l4.y);
  splitbf(f.z, h4.z, l4.z);
  splitbf(f.w, h4.w, l4.w);
  int blk = k0 >> 5, ch = (k0 & 31) >> 3, off = k0 & 7, key = n & 7;
  unsigned short* rowp = Wot + (size_t)n * 2048 + blk * 64;
  *(ushort4*)(rowp + ((ch ^ key)) * 8 + off) = h4;
  *(ushort4*)(rowp + (((ch + 4) ^ key)) * 8 + off) = l4;
}

// ---------------------------------------------------------------------------
// Single-barrier dbuf split-MFMA projection GEMM. 128x128, BK=32.
// Loop: write As[c]<-aregs | sync | issue areg(k+1)+gldsB(k+1)->Bs[c^1] |
// compute(As[c],Bs[c]). The barrier drains only loads aged one compute phase.
// LDS 64 KB -> 2 blocks/CU. grid (8, 32, 3).
// ---------------------------------------------------------------------------
__global__ __launch_bounds__(256)
void proj_gemm(const float* __restrict__ Qin, const float* __restrict__ Kin,
               const float* __restrict__ Vin,
               const unsigned short* __restrict__ Wqt,
               const unsigned short* __restrict__ Wkt,
               const unsigned short* __restrict__ Wvt,
               const float* __restrict__ bq, const float* __restrict__ bk,
               const float* __restrict__ bv, unsigned short* __restrict__ q_all,
               unsigned short* __restrict__ k_all,
               unsigned short* __restrict__ vt) {
  const int ntile = blockIdx.x, mt = blockIdx.y, z = blockIdx.z;
  const float* A = (z == 0 ? Qin : z == 1 ? Kin : Vin);
  const unsigned short* B = (z == 0 ? Wqt : z == 1 ? Wkt : Wvt);
  const float* bias = (z == 0 ? bq : z == 1 ? bk : bv);

  __shared__ alignas(16) unsigned short As[2][128 * 64];
  __shared__ alignas(16) unsigned short Bs[2][128 * 64];

  const int tid = threadIdx.x;
  const int lane = tid & 63, w = tid >> 6;
  const int l15 = lane & 15, quad = lane >> 4;
  const int wm = (w & 1) * 64, wn = (w >> 1) * 64;
  const int kx = l15 & 7;

  const float* Ap = A + (size_t)(mt * 128) * DM;
  const unsigned short* Bp = B + (size_t)(ntile * 128) * 2048;

  float4 areg[4];
#pragma unroll
  for (int it = 0; it < 4; ++it) {
    int c = tid + it * 256;
    int r = c >> 3, seg = c & 7;
    areg[it] = *(const float4*)(Ap + (size_t)r * DM + seg * 4);
  }
#pragma unroll
  for (int it = 0; it < 4; ++it) {
    int s = tid + it * 256;
    int r = s >> 3, seg = s & 7;
    gld16(Bp + (size_t)r * 2048 + seg * 8, &Bs[0][s * 8]);
  }

  f32x4 acc[4][4];
#pragma unroll
  for (int i = 0; i < 4; ++i)
#pragma unroll
    for (int j = 0; j < 4; ++j) acc[i][j] = (f32x4){0.f, 0.f, 0.f, 0.f};

  int cur = 0;
  for (int kk = 0; kk < 32; ++kk) {
    // write As[cur] from aregs (waits aregs only; B-glds keep flying)
#pragma unroll
    for (int it = 0; it < 4; ++it) {
      int c = tid + it * 256;
      int r = c >> 3, seg = c & 7;
      int key = r & 7, ch = seg >> 1, off = (seg & 1) * 4;
      ushort4 h4, l4;
      splitbf(areg[it].x, h4.x, l4.x);
      splitbf(areg[it].y, h4.y, l4.y);
      splitbf(areg[it].z, h4.z, l4.z);
      splitbf(areg[it].w, h4.w, l4.w);
      *(ushort4*)&As[cur][r * 64 + ((ch ^ key)) * 8 + off] = h4;
      *(ushort4*)&As[cur][r * 64 + (((ch + 4) ^ key)) * 8 + off] = l4;
    }
    __syncthreads();  // drains As writes + aged B-glds(kk); k+1 not yet issued

    if (kk + 1 < 32) {
      int k0n = (kk + 1) * 32;
#pragma unroll
      for (int it = 0; it < 4; ++it) {
        int c = tid + it * 256;
        int r = c >> 3, seg = c & 7;
        areg[it] = *(const float4*)(Ap + (size_t)r * DM + k0n + seg * 4);
      }
#pragma unroll
      for (int it = 0; it < 4; ++it) {
        int s = tid + it * 256;
        int r = s >> 3, seg = s & 7;
        gld16(Bp + (size_t)r * 2048 + (k0n >> 5) * 64 + seg * 8,
              &Bs[cur ^ 1][s * 8]);
      }
    }

    bf16x8 ah[4], al[4];
#pragma unroll
    for (int i = 0; i < 4; ++i) {
      const unsigned short* p = &As[cur][(wm + i * 16 + l15) * 64];
      ah[i] = *(const bf16x8*)(p + ((quad ^ kx)) * 8);
      al[i] = *(const bf16x8*)(p + (((quad + 4) ^ kx)) * 8);
    }
#pragma unroll
    for (int j = 0; j < 4; ++j) {
      const unsigned short* p = &Bs[cur][(wn + j * 16 + l15) * 64];
      bf16x8 bh = *(const bf16x8*)(p + ((quad ^ kx)) * 8);
      bf16x8 bl = *(const bf16x8*)(p + (((quad + 4) ^ kx)) * 8);
#pragma unroll
      for (int i = 0; i < 4; ++i) {
        acc[i][j] = __builtin_amdgcn_mfma_f32_16x16x32_bf16(ah[i], bh, acc[i][j], 0, 0, 0);
        acc[i][j] = __builtin_amdgcn_mfma_f32_16x16x32_bf16(al[i], bh, acc[i][j], 0, 0, 0);
        acc[i][j] = __builtin_amdgcn_mfma_f32_16x16x32_bf16(ah[i], bl, acc[i][j], 0, 0, 0);
      }
    }
    cur ^= 1;
  }

  if (z <= 1) {
    unsigned short* dst = (z == 0 ? q_all : k_all);
#pragma unroll
    for (int i = 0; i < 4; ++i)
#pragma unroll
      for (int j = 0; j < 4; ++j) {
        int n = ntile * 128 + wn + j * 16 + l15;
        int hh_ = n >> 6, d = n & 63;
        int chi = (d >> 5) * 8 + ((d & 31) >> 3);
        float bn = bias[n];
#pragma unroll
        for (int r = 0; r < 4; ++r) {
          int m = mt * 128 + wm + i * 16 + quad * 4 + r;
          int key = m & 15;
          size_t rb = (size_t)m * 2048 + hh_ * 128;
          unsigned short hv, lv;
          splitbf(acc[i][j][r] + bn, hv, lv);
          dst[rb + ((chi ^ key)) * 8 + (d & 7)] = hv;
          dst[rb + (((chi + 4) ^ key)) * 8 + (d & 7)] = lv;
        }
      }
  } else {
#pragma unroll
    for (int i = 0; i < 4; ++i)
#pragma unroll
      for (int j = 0; j < 4; ++j) {
        int n = ntile * 128 + wn + j * 16 + l15;
        int h = n >> 6, d = n & 63;
        float bn = bias[n];
        int m0 = mt * 128 + wm + i * 16 + quad * 4;
        int b = m0 >> 11, s0_ = m0 & 2047;
        int kt = s0_ >> 6, sl = s0_ & 63;
        int ch = sl >> 3, off = sl & 7, key = d & 15;
        ushort4 h4, l4;
        splitbf(acc[i][j][0] + bn, h4.x, l4.x);
        splitbf(acc[i][j][1] + bn, h4.y, l4.y);
        splitbf(acc[i][j][2] + bn, h4.z, l4.z);
        splitbf(acc[i][j][3] + bn, h4.w, l4.w);
        size_t base =
            (size_t)(b * NH + h) * 262144 + (size_t)d * 4096 + kt * 128;
        *(ushort4*)(vt + base + ((ch ^ key)) * 8 + off) = h4;
        *(ushort4*)(vt + base + (((ch + 8) ^ key)) * 8 + off) = l4;
      }
  }
}

// ---------------------------------------------------------------------------
// Single-barrier dbuf output GEMM: both operands glds (a_all packed, Wot
// pre-split), zero staging VALU. Tile 64m x 128n, BK=32. grid (8, 64) = 512.
// LDS 48 KB.
// ---------------------------------------------------------------------------
__global__ __launch_bounds__(256)
void out_gemm(const unsigned short* __restrict__ a_all,
              const unsigned short* __restrict__ Wot,
              const float* __restrict__ bo, float* __restrict__ out) {
  const int ntile = blockIdx.x, mt = blockIdx.y;

  __shared__ alignas(16) unsigned short As[2][64 * 64];
  __shared__ alignas(16) unsigned short Bs[2][128 * 64];

  const int tid = threadIdx.x;
  const int lane = tid & 63, w = tid >> 6;
  const int l15 = lane & 15, quad = lane >> 4;
  const int wn = w * 32;
  const int kx = l15 & 7;

  const unsigned short* Ap = a_all + (size_t)(mt * 64) * 2048;
  const unsigned short* Bp = Wot + (size_t)(ntile * 128) * 2048;

#pragma unroll
  for (int it = 0; it < 2; ++it) {
    int s = tid + it * 256;
    int r = s >> 3, seg = s & 7;
    gld16(Ap + (size_t)r * 2048 + seg * 8, &As[0][s * 8]);
  }
#pragma unroll
  for (int it = 0; it < 4; ++it) {
    int s = tid + it * 256;
    int r = s >> 3, seg = s & 7;
    gld16(Bp + (size_t)r * 2048 + seg * 8, &Bs[0][s * 8]);
  }

  f32x4 acc[4][2];
#pragma unroll
  for (int i = 0; i < 4; ++i)
#pragma unroll
    for (int j = 0; j < 2; ++j) acc[i][j] = (f32x4){0.f, 0.f, 0.f, 0.f};

  int cur = 0;
  for (int kk = 0; kk < 32; ++kk) {
    __syncthreads();  // drains glds(kk), aged one compute phase

    if (kk + 1 < 32) {
      int blk = ((kk + 1)) * 64;  // (k0n>>5)*64 with k0n=(kk+1)*32
#pragma unroll
      for (int it = 0; it < 2; ++it) {
        int s = tid + it * 256;
        int r = s >> 3, seg = s & 7;
        gld16(Ap + (size_t)r * 2048 + blk + seg * 8, &As[cur ^ 1][s * 8]);
      }
#pragma unroll
      for (int it = 0; it < 4; ++it) {
        int s = tid + it * 256;
        int r = s >> 3, seg = s & 7;
        gld16(Bp + (size_t)r * 2048 + blk + seg * 8, &Bs[cur ^ 1][s * 8]);
      }
    }

    bf16x8 ah[4], al[4];
#pragma unroll
    for (int i = 0; i < 4; ++i) {
      const unsigned short* p = &As[cur][(i * 16 + l15) * 64];
      ah[i] = *(const bf16x8*)(p + ((quad ^ kx)) * 8);
      al[i] = *(const bf16x8*)(p + (((quad + 4) ^ kx)) * 8);
    }
#pragma unroll
    for (int j = 0; j < 2; ++j) {
      const unsigned short* p = &Bs[cur][(wn + j * 16 + l15) * 64];
      bf16x8 bh = *(const bf16x8*)(p + ((quad ^ kx)) * 8);
      bf16x8 bl = *(const bf16x8*)(p + (((quad + 4) ^ kx)) * 8);
#pragma unroll
      for (int i = 0; i < 4; ++i) {
        acc[i][j] = __builtin_amdgcn_mfma_f32_16x16x32_bf16(ah[i], bh, acc[i][j], 0, 0, 0);
        acc[i][j] = __builtin_amdgcn_mfma_f32_16x16x32_bf16(al[i], bh, acc[i][j], 0, 0, 0);
        acc[i][j] = __builtin_amdgcn_mfma_f32_16x16x32_bf16(ah[i], bl, acc[i][j], 0, 0, 0);
      }
    }
    cur ^= 1;
  }

#pragma unroll
  for (int i = 0; i < 4; ++i)
#pragma unroll
    for (int j = 0; j < 2; ++j) {
      int n = ntile * 128 + wn + j * 16 + l15;
      float bn = bo[n];
#pragma unroll
      for (int r = 0; r < 4; ++r) {
        int m = mt * 64 + i * 16 + quad * 4 + r;
        out[(size_t)m * DM + n] = acc[i][j][r] + bn;
      }
    }
}

// ---------------------------------------------------------------------------
// MFMA flash attention (unchanged from round 6).
// ---------------------------------------------------------------------------
__global__ __launch_bounds__(256)
void attn_kernel(const unsigned short* __restrict__ q_all,
                 const unsigned short* __restrict__ k_all,
                 const unsigned short* __restrict__ vt,
                 unsigned short* __restrict__ a_all) {
  const int qt = blockIdx.x, h = blockIdx.y, b = blockIdx.z;
  const unsigned short* vp = vt + (size_t)(b * NH + h) * 262144;

  __shared__ alignas(16) unsigned short Ks[64 * 128];
  __shared__ alignas(16) unsigned short Vs[64 * 128];
  __shared__ alignas(16) unsigned short Ps[128 * 64];

  const int tid = threadIdx.x;
  const int lane = tid & 63;
  const int w = tid >> 6;
  const int l15 = lane & 15;
  const int quad = lane >> 4;

  bf16x8 qf[2][2][2];
#pragma unroll
  for (int rt = 0; rt < 2; ++rt) {
    const unsigned short* qrow =
        q_all + (size_t)(b * SLEN + qt * 128 + w * 32 + rt * 16 + l15) * 2048 +
        h * 128;
#pragma unroll
    for (int kb = 0; kb < 2; ++kb) {
      qf[rt][kb][0] = *(const bf16x8*)(qrow + ((kb * 8 + quad) ^ l15) * 8);
      qf[rt][kb][1] = *(const bf16x8*)(qrow + ((kb * 8 + quad + 4) ^ l15) * 8);
    }
  }

  f32x4 o[2][4];
  float lpart[2][4];
#pragma unroll
  for (int rt = 0; rt < 2; ++rt)
#pragma unroll
    for (int nt = 0; nt < 4; ++nt) {
      o[rt][nt] = (f32x4){0.f, 0.f, 0.f, 0.f};
      lpart[rt][nt] = 0.f;
    }

  for (int kt = 0; kt < STILES; ++kt) {
    const unsigned short* ksrc =
        k_all + (size_t)(b * SLEN + kt * 64) * 2048 + h * 128;
#pragma unroll
    for (int it = 0; it < 4; ++it) {
      int ss = it * 256 + tid;
      int r = ss >> 4, p = ss & 15;
      gld16(ksrc + (size_t)r * 2048 + p * 8, &Ks[ss * 8]);
    }
#pragma unroll
    for (int it = 0; it < 4; ++it) {
      int ss = it * 256 + tid;
      int d = ss >> 4, p = ss & 15;
      gld16(vp + (size_t)d * 4096 + kt * 128 + p * 8, &Vs[ss * 8]);
    }
    __syncthreads();

    f32x4 sc[2][4];
#pragma unroll
    for (int rt = 0; rt < 2; ++rt)
#pragma unroll
      for (int ct = 0; ct < 4; ++ct) sc[rt][ct] = (f32x4){0.f, 0.f, 0.f, 0.f};
#pragma unroll
    for (int ct = 0; ct < 4; ++ct) {
      const unsigned short* kbase = &Ks[(ct * 16 + l15) * 128];
#pragma unroll
      for (int kb = 0; kb < 2; ++kb) {
        bf16x8 kh = *(const bf16x8*)(kbase + ((kb * 8 + quad) ^ l15) * 8);
        bf16x8 kl = *(const bf16x8*)(kbase + ((kb * 8 + quad + 4) ^ l15) * 8);
#pragma unroll
        for (int rt = 0; rt < 2; ++rt) {
          sc[rt][ct] = __builtin_amdgcn_mfma_f32_16x16x32_bf16(qf[rt][kb][0], kh, sc[rt][ct], 0, 0, 0);
          sc[rt][ct] = __builtin_amdgcn_mfma_f32_16x16x32_bf16(qf[rt][kb][0], kl, sc[rt][ct], 0, 0, 0);
          sc[rt][ct] = __builtin_amdgcn_mfma_f32_16x16x32_bf16(qf[rt][kb][1], kh, sc[rt][ct], 0, 0, 0);
        }
      }
    }

#pragma unroll
    for (int rt = 0; rt < 2; ++rt)
#pragma unroll
      for (int ct = 0; ct < 4; ++ct)
#pragma unroll
        for (int r = 0; r < 4; ++r) {
          float e = __expf(sc[rt][ct][r] * 0.125f);
          lpart[rt][r] += e;
          int prow = w * 32 + rt * 16 + quad * 4 + r;
          int pkey = (prow >> 1) & 7;
          Ps[prow * 64 + (((ct * 2 + (l15 >> 3)) ^ pkey)) * 8 + (l15 & 7)] =
              f2bf(e);
        }
    __syncthreads();

    int rk = (l15 >> 1) & 7;
#pragma unroll
    for (int kb = 0; kb < 2; ++kb) {
      bf16x8 pf[2];
#pragma unroll
      for (int rt = 0; rt < 2; ++rt)
        pf[rt] = *(const bf16x8*)(&Ps[(w * 32 + rt * 16 + l15) * 64 +
                                      (((kb * 4 + quad) ^ rk)) * 8]);
#pragma unroll
      for (int nt = 0; nt < 4; ++nt) {
        const unsigned short* vb = &Vs[(nt * 16 + l15) * 128];
        bf16x8 vh = *(const bf16x8*)(vb + (((kb * 4 + quad) ^ l15)) * 8);
        bf16x8 vl = *(const bf16x8*)(vb + (((kb * 4 + quad + 8) ^ l15)) * 8);
#pragma unroll
        for (int rt = 0; rt < 2; ++rt) {
          o[rt][nt] = __builtin_amdgcn_mfma_f32_16x16x32_bf16(pf[rt], vh, o[rt][nt], 0, 0, 0);
          o[rt][nt] = __builtin_amdgcn_mfma_f32_16x16x32_bf16(pf[rt], vl, o[rt][nt], 0, 0, 0);
        }
      }
    }
    __syncthreads();
  }

#pragma unroll
  for (int rt = 0; rt < 2; ++rt) {
    float inv[4];
#pragma unroll
    for (int r = 0; r < 4; ++r) {
      float lv = lpart[rt][r];
#pragma unroll
      for (int m = 1; m < 16; m <<= 1) lv += __shfl_xor(lv, m, 64);
      inv[r] = 1.f / lv;
    }
#pragma unroll
    for (int nt = 0; nt < 4; ++nt) {
      int c = h * 64 + nt * 16 + l15;
      int Bb = c >> 5;
      int d32 = c & 31;
      int ch = d32 >> 3, off = d32 & 7;
#pragma unroll
      for (int r = 0; r < 4; ++r) {
        float val = o[rt][nt][r] * inv[r];
        int srow = qt * 128 + w * 32 + rt * 16 + quad * 4 + r;
        int key = srow & 7;
        size_t g = (size_t)(b * SLEN + srow) * 2048 + Bb * 64;
        unsigned short hv, lv2;
        splitbf(val, hv, lv2);
        a_all[g + ((ch ^ key)) * 8 + off] = hv;
        a_all[g + (((ch + 4) ^ key)) * 8 + off] = lv2;
      }
    }
  }
}

extern "C" void kernel_launch(void* const* d_in, const int* in_sizes, int n_in,
                              void* d_out, int out_size, void* d_ws,
                              size_t ws_size, hipStream_t stream) {
  (void)in_sizes; (void)n_in; (void)out_size; (void)ws_size;
  const float* Q = (const float*)d_in[0];
  const float* K = (const float*)d_in[1];
  const float* V = (const float*)d_in[2];
  const float* Wq = (const float*)d_in[3];
  const float* bq = (const float*)d_in[4];
  const float* Wk = (const float*)d_in[5];
  const float* bk = (const float*)d_in[6];
  const float* Wv = (const float*)d_in[7];
  const float* bv = (const float*)d_in[8];
  const float* Wo = (const float*)d_in[9];
  const float* bo = (const float*)d_in[10];
  float* out = (float*)d_out;

  unsigned short* us = (unsigned short*)d_ws;
  const size_t M8 = 8u * 1024 * 1024;
  unsigned short* q_all = us;
  unsigned short* k_all = us + M8;
  unsigned short* vt = us + 2 * M8;
  unsigned short* a_all = us + 3 * M8;
  unsigned short* Wqt = a_all;  // dead by the time attn writes a_all
  unsigned short* Wkt = a_all + 2 * 1024 * 1024;
  unsigned short* Wvt = a_all + 4 * 1024 * 1024;
  unsigned short* Wot = q_all;  // q_all dead after attn; convert_wo runs then

  convert_w<<<dim3(16, 16, 3), 256, 0, stream>>>(Wq, Wk, Wv, Wqt, Wkt, Wvt);
  proj_gemm<<<dim3(8, 32, 3), 256, 0, stream>>>(Q, K, V, Wqt, Wkt, Wvt, bq,
                                                bk, bv, q_all, k_all, vt);
  attn_kernel<<<dim3(SLEN / 128, NH, BATCH), 256, 0, stream>>>(q_all, k_all,
                                                               vt, a_all);
  convert_wo<<<dim3(1024), 256, 0, stream>>>(Wo, Wot);
  out_gemm<<<dim3(8, 64), 256, 0, stream>>>(a_all, Wot, bo, out);
}

// Round 8
// 367.803 us; speedup vs baseline: 1.7463x; 1.0089x over previous
//
#include <hip/hip_runtime.h>
#include <math.h>

#define BATCH 2
#define SLEN 2048
#define DM 1024
#define NH 16
#define DK 64
#define STILES (SLEN / 64)  // 32

typedef __attribute__((ext_vector_type(8))) __bf16 bf16x8;
typedef __attribute__((ext_vector_type(4))) float f32x4;

__device__ __forceinline__ unsigned short f2bf(float x) {  // round-nearest
  unsigned u = __builtin_bit_cast(unsigned, x);
  unsigned r = (u + 0x7fffu + ((u >> 16) & 1u)) >> 16;
  return (unsigned short)r;
}
// cheap truncation split: x ~= hi + lo to ~2^-16 relative
__device__ __forceinline__ void splitbf(float x, unsigned short& h,
                                        unsigned short& l) {
  unsigned u = __builtin_bit_cast(unsigned, x);
  h = (unsigned short)(u >> 16);
  float hf = __builtin_bit_cast(float, u & 0xffff0000u);
  l = (unsigned short)(__builtin_bit_cast(unsigned, x - hf) >> 16);
}

// async global->LDS, 16 B per lane
__device__ __forceinline__ void gld16(const unsigned short* g,
                                      unsigned short* l) {
  __builtin_amdgcn_global_load_lds(
      (const __attribute__((address_space(1))) void*)g,
      (__attribute__((address_space(3))) void*)l, 16, 0, 0);
}

// ---------------------------------------------------------------------------
// Weight transpose+split -> Wt[n][packed k], 64-u16 k-blocks [hi32|lo32],
// 16-B chunks XOR-swizzled with key (n&7).
// ---------------------------------------------------------------------------
__global__ __launch_bounds__(256)
void convert_w(const float* __restrict__ Wq, const float* __restrict__ Wk,
               const float* __restrict__ Wv, unsigned short* __restrict__ Wqt,
               unsigned short* __restrict__ Wkt,
               unsigned short* __restrict__ Wvt) {
  const int kb = blockIdx.x, h = blockIdx.y, z = blockIdx.z;
  const float* W = (z == 0 ? Wq : z == 1 ? Wk : Wv) +
                   ((size_t)h * DM + kb * 64) * DK;
  unsigned short* D = (z == 0 ? Wqt : z == 1 ? Wkt : Wvt);

  __shared__ float T[64][65];
  const int tid = threadIdx.x;
  {
    int r = tid >> 2, c0 = (tid & 3) * 16;
#pragma unroll
    for (int i = 0; i < 4; ++i) {
      float4 f = *(const float4*)(W + (size_t)r * DK + c0 + i * 4);
      T[r][c0 + i * 4 + 0] = f.x;
      T[r][c0 + i * 4 + 1] = f.y;
      T[r][c0 + i * 4 + 2] = f.z;
      T[r][c0 + i * 4 + 3] = f.w;
    }
  }
  __syncthreads();
  int j = tid >> 2, p = tid & 3;
  int n = h * 64 + j;
  int kloc = p * 16;
  unsigned short hi[16], lo[16];
#pragma unroll
  for (int i = 0; i < 16; ++i) splitbf(T[kloc + i][j], hi[i], lo[i]);
  int kglob = kb * 64 + kloc;
  int blk = kglob >> 5;
  int c0 = (kglob & 31) >> 3;
  int key = n & 7;
  unsigned short* rowp = D + (size_t)n * 2048 + blk * 64;
  uint4 u0, u1;
  u0.x = (unsigned)hi[0] | ((unsigned)hi[1] << 16);
  u0.y = (unsigned)hi[2] | ((unsigned)hi[3] << 16);
  u0.z = (unsigned)hi[4] | ((unsigned)hi[5] << 16);
  u0.w = (unsigned)hi[6] | ((unsigned)hi[7] << 16);
  u1.x = (unsigned)hi[8] | ((unsigned)hi[9] << 16);
  u1.y = (unsigned)hi[10] | ((unsigned)hi[11] << 16);
  u1.z = (unsigned)hi[12] | ((unsigned)hi[13] << 16);
  u1.w = (unsigned)hi[14] | ((unsigned)hi[15] << 16);
  *(uint4*)(rowp + ((c0 ^ key)) * 8) = u0;
  *(uint4*)(rowp + (((c0 + 1) ^ key)) * 8) = u1;
  u0.x = (unsigned)lo[0] | ((unsigned)lo[1] << 16);
  u0.y = (unsigned)lo[2] | ((unsigned)lo[3] << 16);
  u0.z = (unsigned)lo[4] | ((unsigned)lo[5] << 16);
  u0.w = (unsigned)lo[6] | ((unsigned)lo[7] << 16);
  u1.x = (unsigned)lo[8] | ((unsigned)lo[9] << 16);
  u1.y = (unsigned)lo[10] | ((unsigned)lo[11] << 16);
  u1.z = (unsigned)lo[12] | ((unsigned)lo[13] << 16);
  u1.w = (unsigned)lo[14] | ((unsigned)lo[15] << 16);
  *(uint4*)(rowp + (((c0 + 4) ^ key)) * 8) = u0;
  *(uint4*)(rowp + (((c0 + 5) ^ key)) * 8) = u1;
}

// ---------------------------------------------------------------------------
// X pre-split: X[m][k] fp32 -> Xp[z][m][packed k] (swizzle key m&7).
// grid (4096, 3), block 256.
// ---------------------------------------------------------------------------
__global__ __launch_bounds__(256)
void convert_x(const float* __restrict__ Q, const float* __restrict__ K,
               const float* __restrict__ V, unsigned short* __restrict__ Xp) {
  const int m = blockIdx.x, z = blockIdx.y;
  const float* src = (z == 0 ? Q : z == 1 ? K : V) + (size_t)m * DM;
  unsigned short* dst =
      Xp + (size_t)z * (8u * 1024 * 1024) + (size_t)m * 2048;
  const int k0 = threadIdx.x * 4;
  float4 f = *(const float4*)(src + k0);
  ushort4 h4, l4;
  splitbf(f.x, h4.x, l4.x);
  splitbf(f.y, h4.y, l4.y);
  splitbf(f.z, h4.z, l4.z);
  splitbf(f.w, h4.w, l4.w);
  int blk = k0 >> 5, ch = (k0 & 31) >> 3, off = k0 & 7, key = m & 7;
  unsigned short* rowp = dst + blk * 64;
  *(ushort4*)(rowp + ((ch ^ key)) * 8 + off) = h4;
  *(ushort4*)(rowp + (((ch + 4) ^ key)) * 8 + off) = l4;
}

// ---------------------------------------------------------------------------
// Wo pre-split: Wo[n][k] fp32 -> Wot[n][packed k] (swizzled like Wt).
// Runs AFTER attn (q_all region dead). grid 1024, block 256.
// ---------------------------------------------------------------------------
__global__ __launch_bounds__(256)
void convert_wo(const float* __restrict__ Wo, unsigned short* __restrict__ Wot) {
  const int n = blockIdx.x;
  const int t = threadIdx.x;
  const int k0 = t * 4;
  float4 f = *(const float4*)(Wo + (size_t)n * DM + k0);
  ushort4 h4, l4;
  splitbf(f.x, h4.x, l4.x);
  splitbf(f.y, h4.y, l4.y);
  splitbf(f.z, h4.z, l4.z);
  splitbf(f.w, h4.w, l4.w);
  int blk = k0 >> 5, ch = (k0 & 31) >> 3, off = k0 & 7, key = n & 7;
  unsigned short* rowp = Wot + (size_t)n * 2048 + blk * 64;
  *(ushort4*)(rowp + ((ch ^ key)) * 8 + off) = h4;
  *(ushort4*)(rowp + (((ch + 4) ^ key)) * 8 + off) = l4;
}

// ---------------------------------------------------------------------------
// Pure-glds dbuf proj GEMM (m97 structure x3 density): both operands packed
// bf16 via global_load_lds, single barrier, zero staging VALU.
// 128x128, BK=32; LDS 64 KB -> 2 blocks/CU. grid (8, 32, 3).
// ---------------------------------------------------------------------------
__global__ __launch_bounds__(256)
void proj_gemm(const unsigned short* __restrict__ Xp,
               const unsigned short* __restrict__ Wqt,
               const unsigned short* __restrict__ Wkt,
               const unsigned short* __restrict__ Wvt,
               const float* __restrict__ bq, const float* __restrict__ bk,
               const float* __restrict__ bv, unsigned short* __restrict__ q_all,
               unsigned short* __restrict__ k_all,
               unsigned short* __restrict__ vt) {
  const int ntile = blockIdx.x, mt = blockIdx.y, z = blockIdx.z;
  const unsigned short* B = (z == 0 ? Wqt : z == 1 ? Wkt : Wvt);
  const float* bias = (z == 0 ? bq : z == 1 ? bk : bv);

  __shared__ alignas(16) unsigned short As[2][128 * 64];
  __shared__ alignas(16) unsigned short Bs[2][128 * 64];

  const int tid = threadIdx.x;
  const int lane = tid & 63, w = tid >> 6;
  const int l15 = lane & 15, quad = lane >> 4;
  const int wm = (w & 1) * 64, wn = (w >> 1) * 64;
  const int kx = l15 & 7;

  const unsigned short* Ap =
      Xp + (size_t)z * (8u * 1024 * 1024) + (size_t)(mt * 128) * 2048;
  const unsigned short* Bp = B + (size_t)(ntile * 128) * 2048;

#pragma unroll
  for (int it = 0; it < 4; ++it) {
    int s = tid + it * 256;
    int r = s >> 3, seg = s & 7;
    gld16(Ap + (size_t)r * 2048 + seg * 8, &As[0][s * 8]);
    gld16(Bp + (size_t)r * 2048 + seg * 8, &Bs[0][s * 8]);
  }

  f32x4 acc[4][4];
#pragma unroll
  for (int i = 0; i < 4; ++i)
#pragma unroll
    for (int j = 0; j < 4; ++j) acc[i][j] = (f32x4){0.f, 0.f, 0.f, 0.f};

  int cur = 0;
  for (int kk = 0; kk < 32; ++kk) {
    __syncthreads();  // drains glds(kk), aged one compute phase

    if (kk + 1 < 32) {
      int blk = (kk + 1) * 64;
#pragma unroll
      for (int it = 0; it < 4; ++it) {
        int s = tid + it * 256;
        int r = s >> 3, seg = s & 7;
        gld16(Ap + (size_t)r * 2048 + blk + seg * 8, &As[cur ^ 1][s * 8]);
        gld16(Bp + (size_t)r * 2048 + blk + seg * 8, &Bs[cur ^ 1][s * 8]);
      }
    }

    bf16x8 ah[4], al[4];
#pragma unroll
    for (int i = 0; i < 4; ++i) {
      const unsigned short* p = &As[cur][(wm + i * 16 + l15) * 64];
      ah[i] = *(const bf16x8*)(p + ((quad ^ kx)) * 8);
      al[i] = *(const bf16x8*)(p + (((quad + 4) ^ kx)) * 8);
    }
#pragma unroll
    for (int j = 0; j < 4; ++j) {
      const unsigned short* p = &Bs[cur][(wn + j * 16 + l15) * 64];
      bf16x8 bh = *(const bf16x8*)(p + ((quad ^ kx)) * 8);
      bf16x8 bl = *(const bf16x8*)(p + (((quad + 4) ^ kx)) * 8);
#pragma unroll
      for (int i = 0; i < 4; ++i) {
        acc[i][j] = __builtin_amdgcn_mfma_f32_16x16x32_bf16(ah[i], bh, acc[i][j], 0, 0, 0);
        acc[i][j] = __builtin_amdgcn_mfma_f32_16x16x32_bf16(al[i], bh, acc[i][j], 0, 0, 0);
        acc[i][j] = __builtin_amdgcn_mfma_f32_16x16x32_bf16(ah[i], bl, acc[i][j], 0, 0, 0);
      }
    }
    cur ^= 1;
  }

  if (z <= 1) {
    unsigned short* dst = (z == 0 ? q_all : k_all);
#pragma unroll
    for (int i = 0; i < 4; ++i)
#pragma unroll
      for (int j = 0; j < 4; ++j) {
        int n = ntile * 128 + wn + j * 16 + l15;
        int hh_ = n >> 6, d = n & 63;
        int chi = (d >> 5) * 8 + ((d & 31) >> 3);
        float bn = bias[n];
#pragma unroll
        for (int r = 0; r < 4; ++r) {
          int m = mt * 128 + wm + i * 16 + quad * 4 + r;
          int key = m & 15;
          size_t rb = (size_t)m * 2048 + hh_ * 128;
          unsigned short hv, lv;
          splitbf(acc[i][j][r] + bn, hv, lv);
          dst[rb + ((chi ^ key)) * 8 + (d & 7)] = hv;
          dst[rb + (((chi + 4) ^ key)) * 8 + (d & 7)] = lv;
        }
      }
  } else {
#pragma unroll
    for (int i = 0; i < 4; ++i)
#pragma unroll
      for (int j = 0; j < 4; ++j) {
        int n = ntile * 128 + wn + j * 16 + l15;
        int h = n >> 6, d = n & 63;
        float bn = bias[n];
        int m0 = mt * 128 + wm + i * 16 + quad * 4;
        int b = m0 >> 11, s0_ = m0 & 2047;
        int kt = s0_ >> 6, sl = s0_ & 63;
        int ch = sl >> 3, off = sl & 7, key = d & 15;
        ushort4 h4, l4;
        splitbf(acc[i][j][0] + bn, h4.x, l4.x);
        splitbf(acc[i][j][1] + bn, h4.y, l4.y);
        splitbf(acc[i][j][2] + bn, h4.z, l4.z);
        splitbf(acc[i][j][3] + bn, h4.w, l4.w);
        size_t base =
            (size_t)(b * NH + h) * 262144 + (size_t)d * 4096 + kt * 128;
        *(ushort4*)(vt + base + ((ch ^ key)) * 8 + off) = h4;
        *(ushort4*)(vt + base + (((ch + 8) ^ key)) * 8 + off) = l4;
      }
  }
}

// ---------------------------------------------------------------------------
// Single-barrier dbuf output GEMM (unchanged from R7).
// ---------------------------------------------------------------------------
__global__ __launch_bounds__(256)
void out_gemm(const unsigned short* __restrict__ a_all,
              const unsigned short* __restrict__ Wot,
              const float* __restrict__ bo, float* __restrict__ out) {
  const int ntile = blockIdx.x, mt = blockIdx.y;

  __shared__ alignas(16) unsigned short As[2][64 * 64];
  __shared__ alignas(16) unsigned short Bs[2][128 * 64];

  const int tid = threadIdx.x;
  const int lane = tid & 63, w = tid >> 6;
  const int l15 = lane & 15, quad = lane >> 4;
  const int wn = w * 32;
  const int kx = l15 & 7;

  const unsigned short* Ap = a_all + (size_t)(mt * 64) * 2048;
  const unsigned short* Bp = Wot + (size_t)(ntile * 128) * 2048;

#pragma unroll
  for (int it = 0; it < 2; ++it) {
    int s = tid + it * 256;
    int r = s >> 3, seg = s & 7;
    gld16(Ap + (size_t)r * 2048 + seg * 8, &As[0][s * 8]);
  }
#pragma unroll
  for (int it = 0; it < 4; ++it) {
    int s = tid + it * 256;
    int r = s >> 3, seg = s & 7;
    gld16(Bp + (size_t)r * 2048 + seg * 8, &Bs[0][s * 8]);
  }

  f32x4 acc[4][2];
#pragma unroll
  for (int i = 0; i < 4; ++i)
#pragma unroll
    for (int j = 0; j < 2; ++j) acc[i][j] = (f32x4){0.f, 0.f, 0.f, 0.f};

  int cur = 0;
  for (int kk = 0; kk < 32; ++kk) {
    __syncthreads();

    if (kk + 1 < 32) {
      int blk = (kk + 1) * 64;
#pragma unroll
      for (int it = 0; it < 2; ++it) {
        int s = tid + it * 256;
        int r = s >> 3, seg = s & 7;
        gld16(Ap + (size_t)r * 2048 + blk + seg * 8, &As[cur ^ 1][s * 8]);
      }
#pragma unroll
      for (int it = 0; it < 4; ++it) {
        int s = tid + it * 256;
        int r = s >> 3, seg = s & 7;
        gld16(Bp + (size_t)r * 2048 + blk + seg * 8, &Bs[cur ^ 1][s * 8]);
      }
    }

    bf16x8 ah[4], al[4];
#pragma unroll
    for (int i = 0; i < 4; ++i) {
      const unsigned short* p = &As[cur][(i * 16 + l15) * 64];
      ah[i] = *(const bf16x8*)(p + ((quad ^ kx)) * 8);
      al[i] = *(const bf16x8*)(p + (((quad + 4) ^ kx)) * 8);
    }
#pragma unroll
    for (int j = 0; j < 2; ++j) {
      const unsigned short* p = &Bs[cur][(wn + j * 16 + l15) * 64];
      bf16x8 bh = *(const bf16x8*)(p + ((quad ^ kx)) * 8);
      bf16x8 bl = *(const bf16x8*)(p + (((quad + 4) ^ kx)) * 8);
#pragma unroll
      for (int i = 0; i < 4; ++i) {
        acc[i][j] = __builtin_amdgcn_mfma_f32_16x16x32_bf16(ah[i], bh, acc[i][j], 0, 0, 0);
        acc[i][j] = __builtin_amdgcn_mfma_f32_16x16x32_bf16(al[i], bh, acc[i][j], 0, 0, 0);
        acc[i][j] = __builtin_amdgcn_mfma_f32_16x16x32_bf16(ah[i], bl, acc[i][j], 0, 0, 0);
      }
    }
    cur ^= 1;
  }

#pragma unroll
  for (int i = 0; i < 4; ++i)
#pragma unroll
    for (int j = 0; j < 2; ++j) {
      int n = ntile * 128 + wn + j * 16 + l15;
      float bn = bo[n];
#pragma unroll
      for (int r = 0; r < 4; ++r) {
        int m = mt * 64 + i * 16 + quad * 4 + r;
        out[(size_t)m * DM + n] = acc[i][j][r] + bn;
      }
    }
}

// ---------------------------------------------------------------------------
// MFMA flash attention with K/V prefetch double-buffer (80 KB -> 2 blocks/CU).
// glds(kt+1) issued right after the first sync -> aged ~QK+softmax before the
// next drain. Core math identical to R6/R7.
// ---------------------------------------------------------------------------
__global__ __launch_bounds__(256)
void attn_kernel(const unsigned short* __restrict__ q_all,
                 const unsigned short* __restrict__ k_all,
                 const unsigned short* __restrict__ vt,
                 unsigned short* __restrict__ a_all) {
  const int qt = blockIdx.x, h = blockIdx.y, b = blockIdx.z;
  const unsigned short* vp = vt + (size_t)(b * NH + h) * 262144;

  __shared__ alignas(16) unsigned short Ks[2][64 * 128];
  __shared__ alignas(16) unsigned short Vs[2][64 * 128];
  __shared__ alignas(16) unsigned short Ps[128 * 64];

  const int tid = threadIdx.x;
  const int lane = tid & 63;
  const int w = tid >> 6;
  const int l15 = lane & 15;
  const int quad = lane >> 4;

  bf16x8 qf[2][2][2];
#pragma unroll
  for (int rt = 0; rt < 2; ++rt) {
    const unsigned short* qrow =
        q_all + (size_t)(b * SLEN + qt * 128 + w * 32 + rt * 16 + l15) * 2048 +
        h * 128;
#pragma unroll
    for (int kb = 0; kb < 2; ++kb) {
      qf[rt][kb][0] = *(const bf16x8*)(qrow + ((kb * 8 + quad) ^ l15) * 8);
      qf[rt][kb][1] = *(const bf16x8*)(qrow + ((kb * 8 + quad + 4) ^ l15) * 8);
    }
  }

  // prologue: stage kt=0
  {
    const unsigned short* ksrc = k_all + (size_t)(b * SLEN) * 2048 + h * 128;
#pragma unroll
    for (int it = 0; it < 4; ++it) {
      int ss = it * 256 + tid;
      int r = ss >> 4, p = ss & 15;
      gld16(ksrc + (size_t)r * 2048 + p * 8, &Ks[0][ss * 8]);
    }
#pragma unroll
    for (int it = 0; it < 4; ++it) {
      int ss = it * 256 + tid;
      int d = ss >> 4, p = ss & 15;
      gld16(vp + (size_t)d * 4096 + p * 8, &Vs[0][ss * 8]);
    }
  }

  f32x4 o[2][4];
  float lpart[2][4];
#pragma unroll
  for (int rt = 0; rt < 2; ++rt)
#pragma unroll
    for (int nt = 0; nt < 4; ++nt) {
      o[rt][nt] = (f32x4){0.f, 0.f, 0.f, 0.f};
      lpart[rt][nt] = 0.f;
    }

  int cur = 0;
  for (int kt = 0; kt < STILES; ++kt) {
    __syncthreads();  // glds(kt) done (aged through prev iteration for kt>0)

    if (kt + 1 < STILES) {  // prefetch kt+1 into alt buffers
      const unsigned short* ksrc =
          k_all + (size_t)(b * SLEN + (kt + 1) * 64) * 2048 + h * 128;
#pragma unroll
      for (int it = 0; it < 4; ++it) {
        int ss = it * 256 + tid;
        int r = ss >> 4, p = ss & 15;
        gld16(ksrc + (size_t)r * 2048 + p * 8, &Ks[cur ^ 1][ss * 8]);
      }
#pragma unroll
      for (int it = 0; it < 4; ++it) {
        int ss = it * 256 + tid;
        int d = ss >> 4, p = ss & 15;
        gld16(vp + (size_t)d * 4096 + (kt + 1) * 128 + p * 8,
              &Vs[cur ^ 1][ss * 8]);
      }
    }

    f32x4 sc[2][4];
#pragma unroll
    for (int rt = 0; rt < 2; ++rt)
#pragma unroll
      for (int ct = 0; ct < 4; ++ct) sc[rt][ct] = (f32x4){0.f, 0.f, 0.f, 0.f};
#pragma unroll
    for (int ct = 0; ct < 4; ++ct) {
      const unsigned short* kbase = &Ks[cur][(ct * 16 + l15) * 128];
#pragma unroll
      for (int kb = 0; kb < 2; ++kb) {
        bf16x8 kh = *(const bf16x8*)(kbase + ((kb * 8 + quad) ^ l15) * 8);
        bf16x8 kl = *(const bf16x8*)(kbase + ((kb * 8 + quad + 4) ^ l15) * 8);
#pragma unroll
        for (int rt = 0; rt < 2; ++rt) {
          sc[rt][ct] = __builtin_amdgcn_mfma_f32_16x16x32_bf16(qf[rt][kb][0], kh, sc[rt][ct], 0, 0, 0);
          sc[rt][ct] = __builtin_amdgcn_mfma_f32_16x16x32_bf16(qf[rt][kb][0], kl, sc[rt][ct], 0, 0, 0);
          sc[rt][ct] = __builtin_amdgcn_mfma_f32_16x16x32_bf16(qf[rt][kb][1], kh, sc[rt][ct], 0, 0, 0);
        }
      }
    }

#pragma unroll
    for (int rt = 0; rt < 2; ++rt)
#pragma unroll
      for (int ct = 0; ct < 4; ++ct)
#pragma unroll
        for (int r = 0; r < 4; ++r) {
          float e = __expf(sc[rt][ct][r] * 0.125f);
          lpart[rt][r] += e;
          int prow = w * 32 + rt * 16 + quad * 4 + r;
          int pkey = (prow >> 1) & 7;
          Ps[prow * 64 + (((ct * 2 + (l15 >> 3)) ^ pkey)) * 8 + (l15 & 7)] =
              f2bf(e);
        }
    __syncthreads();  // P visible

    int rk = (l15 >> 1) & 7;
#pragma unroll
    for (int kb = 0; kb < 2; ++kb) {
      bf16x8 pf[2];
#pragma unroll
      for (int rt = 0; rt < 2; ++rt)
        pf[rt] = *(const bf16x8*)(&Ps[(w * 32 + rt * 16 + l15) * 64 +
                                      (((kb * 4 + quad) ^ rk)) * 8]);
#pragma unroll
      for (int nt = 0; nt < 4; ++nt) {
        const unsigned short* vb = &Vs[cur][(nt * 16 + l15) * 128];
        bf16x8 vh = *(const bf16x8*)(vb + (((kb * 4 + quad) ^ l15)) * 8);
        bf16x8 vl = *(const bf16x8*)(vb + (((kb * 4 + quad + 8) ^ l15)) * 8);
#pragma unroll
        for (int rt = 0; rt < 2; ++rt) {
          o[rt][nt] = __builtin_amdgcn_mfma_f32_16x16x32_bf16(pf[rt], vh, o[rt][nt], 0, 0, 0);
          o[rt][nt] = __builtin_amdgcn_mfma_f32_16x16x32_bf16(pf[rt], vl, o[rt][nt], 0, 0, 0);
        }
      }
    }
    __syncthreads();  // Ps free for next iteration
    cur ^= 1;
  }

#pragma unroll
  for (int rt = 0; rt < 2; ++rt) {
    float inv[4];
#pragma unroll
    for (int r = 0; r < 4; ++r) {
      float lv = lpart[rt][r];
#pragma unroll
      for (int m = 1; m < 16; m <<= 1) lv += __shfl_xor(lv, m, 64);
      inv[r] = 1.f / lv;
    }
#pragma unroll
    for (int nt = 0; nt < 4; ++nt) {
      int c = h * 64 + nt * 16 + l15;
      int Bb = c >> 5;
      int d32 = c & 31;
      int ch = d32 >> 3, off = d32 & 7;
#pragma unroll
      for (int r = 0; r < 4; ++r) {
        float val = o[rt][nt][r] * inv[r];
        int srow = qt * 128 + w * 32 + rt * 16 + quad * 4 + r;
        int key = srow & 7;
        size_t g = (size_t)(b * SLEN + srow) * 2048 + Bb * 64;
        unsigned short hv, lv2;
        splitbf(val, hv, lv2);
        a_all[g + ((ch ^ key)) * 8 + off] = hv;
        a_all[g + (((ch + 4) ^ key)) * 8 + off] = lv2;
      }
    }
  }
}

extern "C" void kernel_launch(void* const* d_in, const int* in_sizes, int n_in,
                              void* d_out, int out_size, void* d_ws,
                              size_t ws_size, hipStream_t stream) {
  (void)in_sizes; (void)n_in; (void)out_size; (void)ws_size;
  const float* Q = (const float*)d_in[0];
  const float* K = (const float*)d_in[1];
  const float* V = (const float*)d_in[2];
  const float* Wq = (const float*)d_in[3];
  const float* bq = (const float*)d_in[4];
  const float* Wk = (const float*)d_in[5];
  const float* bk = (const float*)d_in[6];
  const float* Wv = (const float*)d_in[7];
  const float* bv = (const float*)d_in[8];
  const float* Wo = (const float*)d_in[9];
  const float* bo = (const float*)d_in[10];
  float* out = (float*)d_out;

  // ws layout (u16 units), 112 MB total:
  //   q_all [0,8M)  k_all [8M,16M)  vt [16M,24M)
  //   a_all [24M,32M) -- Wqt/Wkt/Wvt overlaid (dead before attn writes a_all)
  //   Xp    [32M,56M) -- 3x 8M u16 packed split inputs (dead after proj)
  //   Wot overlays q_all (dead after attn)
  unsigned short* us = (unsigned short*)d_ws;
  const size_t M8 = 8u * 1024 * 1024;
  unsigned short* q_all = us;
  unsigned short* k_all = us + M8;
  unsigned short* vt = us + 2 * M8;
  unsigned short* a_all = us + 3 * M8;
  unsigned short* Wqt = a_all;
  unsigned short* Wkt = a_all + 2 * 1024 * 1024;
  unsigned short* Wvt = a_all + 4 * 1024 * 1024;
  unsigned short* Xp = us + 4 * M8;
  unsigned short* Wot = q_all;

  convert_w<<<dim3(16, 16, 3), 256, 0, stream>>>(Wq, Wk, Wv, Wqt, Wkt, Wvt);
  convert_x<<<dim3(4096, 3), 256, 0, stream>>>(Q, K, V, Xp);
  proj_gemm<<<dim3(8, 32, 3), 256, 0, stream>>>(Xp, Wqt, Wkt, Wvt, bq, bk, bv,
                                                q_all, k_all, vt);
  attn_kernel<<<dim3(SLEN / 128, NH, BATCH), 256, 0, stream>>>(q_all, k_all,
                                                               vt, a_all);
  convert_wo<<<dim3(1024), 256, 0, stream>>>(Wo, Wot);
  out_gemm<<<dim3(8, 64), 256, 0, stream>>>(a_all, Wot, bo, out);
}